// Round 5
// baseline (311.287 us; speedup 1.0000x reference)
//
#include <hip/hip_runtime.h>

typedef unsigned short u16;
typedef __bf16 bf16x8 __attribute__((ext_vector_type(8)));
typedef float f32x4 __attribute__((ext_vector_type(4)));

// ---------- helpers ----------
__device__ __forceinline__ u16 f2bf(float f) {
  union { float f; unsigned u; } v; v.f = f;
  return (u16)((v.u + 0x7fffu + ((v.u >> 16) & 1u)) >> 16);   // RNE
}

#define GLDS16(g, l)                                                          \
  __builtin_amdgcn_global_load_lds(                                           \
      (const __attribute__((address_space(1))) void*)(g),                     \
      (__attribute__((address_space(3))) void*)(l), 16, 0, 0)

#define SBAR()  __builtin_amdgcn_s_barrier()
#define SCHED() __builtin_amdgcn_sched_barrier(0)
#define VMCNT(n) asm volatile("s_waitcnt vmcnt(" #n ")" ::: "memory")

// ---------- sizes ----------
#define NTOK 4096     // B*T
#define DIM  768
#define HID  1536
#define NEXP 8
#define CAPR 9216     // routed slot capacity (8192 + per-expert pad to 128)
#define SHB  9216     // shared-expert slot base
#define NSLOT 13312   // CAPR + NTOK
#define MAXT 104      // max M-tiles: <=72 routed + 32 shared

// ---------- f32 -> bf16 elementwise (x) ----------
__global__ __launch_bounds__(256) void k_cvt_x(const float* __restrict__ src,
                                               u16* __restrict__ dst, int n4) {
  const int i = blockIdx.x * 256 + threadIdx.x;
  if (i >= n4) return;
  const float4 v = ((const float4*)src)[i];
  ushort4 o;
  o.x = f2bf(v.x); o.y = f2bf(v.y); o.z = f2bf(v.z); o.w = f2bf(v.w);
  ((ushort4*)dst)[i] = o;
}

// ---------- fused transpose: 27 slices f32[R][C] -> bf16[C][R], contiguous dst ----------
__global__ __launch_bounds__(256) void k_tr_all(const float* __restrict__ ew1,
                                                const float* __restrict__ sw1,
                                                const float* __restrict__ ew2,
                                                const float* __restrict__ sw2,
                                                const float* __restrict__ eproj,
                                                const float* __restrict__ sproj,
                                                u16* __restrict__ dstBase) {
  __shared__ u16 tile[32][33];
  constexpr size_t SL = (size_t)HID * DIM;
  const int z = blockIdx.z;
  const float* src;
  int R, C, bxx = blockIdx.x, byy = blockIdx.y;
  if (z < 9)       { src = (z < 8) ? ew1 + (size_t)z * SL : sw1; R = DIM; C = HID; }
  else if (z < 18) { const int q = z - 9;  src = (q < 8) ? ew2 + (size_t)q * SL : sw2; R = DIM; C = HID; }
  else             { const int q = z - 18; src = (q < 8) ? eproj + (size_t)q * SL : sproj;
                     R = HID; C = DIM; const int t = bxx; bxx = byy; byy = t; }
  u16* dst = dstBase + (size_t)z * SL;
  const int c0 = bxx * 32, r0 = byy * 32;
  const int tx = threadIdx.x, ty = threadIdx.y;
  #pragma unroll
  for (int i = 0; i < 32; i += 8)
    tile[ty + i][tx] = f2bf(src[(size_t)(r0 + ty + i) * C + c0 + tx]);
  __syncthreads();
  #pragma unroll
  for (int i = 0; i < 32; i += 8)
    dst[(size_t)(c0 + ty + i) * R + r0 + tx] = tile[tx][ty + i];
}

// ---------- router: probs + top-2 (renormalized) ----------
__global__ __launch_bounds__(64) void k_router(const float* __restrict__ x,
                                               const float* __restrict__ rw,
                                               float* __restrict__ probs,
                                               int* __restrict__ topIdx,
                                               float* __restrict__ topW) {
  const int t = blockIdx.x;
  const int lane = threadIdx.x;
  const float* xr = x + (size_t)t * DIM;
  float acc[NEXP] = {0, 0, 0, 0, 0, 0, 0, 0};
  for (int d = lane; d < DIM; d += 64) {
    const float xv = xr[d];
    #pragma unroll
    for (int e = 0; e < NEXP; e++) acc[e] += xv * rw[e * DIM + d];
  }
  #pragma unroll
  for (int e = 0; e < NEXP; e++)
    #pragma unroll
    for (int s = 32; s > 0; s >>= 1) acc[e] += __shfl_xor(acc[e], s, 64);
  if (lane == 0) {
    float mx = acc[0];
    #pragma unroll
    for (int e = 1; e < NEXP; e++) mx = fmaxf(mx, acc[e]);
    float p[NEXP], sum = 0.f;
    #pragma unroll
    for (int e = 0; e < NEXP; e++) { p[e] = expf(acc[e] - mx); sum += p[e]; }
    const float inv = 1.f / sum;
    #pragma unroll
    for (int e = 0; e < NEXP; e++) p[e] *= inv;
    #pragma unroll
    for (int e = 0; e < NEXP; e++) probs[(size_t)t * NEXP + e] = p[e];
    int i1 = 0;
    #pragma unroll
    for (int e = 1; e < NEXP; e++) if (p[e] > p[i1]) i1 = e;
    int i2 = (i1 == 0) ? 1 : 0;
    #pragma unroll
    for (int e = 0; e < NEXP; e++) if (e != i1 && p[e] > p[i2]) i2 = e;
    const float s2 = 1.f / (p[i1] + p[i2]);
    topIdx[2 * t] = i1; topIdx[2 * t + 1] = i2;
    topW[2 * t] = p[i1] * s2; topW[2 * t + 1] = p[i2] * s2;
  }
}

// ---------- per-expert stable compaction (one block per expert) ----------
__global__ __launch_bounds__(256) void k_build(const int* __restrict__ topIdx,
                                               const float* __restrict__ topW,
                                               int* __restrict__ listT,
                                               float* __restrict__ listW,
                                               int* __restrict__ listP,
                                               int* __restrict__ cnt) {
  const int e = blockIdx.x;
  const int tid = threadIdx.x, w = tid >> 6, lane = tid & 63;
  __shared__ int wt[4];
  int base = 0;
  for (int c = 0; c < NTOK / 256; ++c) {
    const int t = c * 256 + tid;
    const int i0 = topIdx[2 * t], i1 = topIdx[2 * t + 1];
    const int pr = (i0 == e) ? 1 : ((i1 == e) ? 2 : 0);
    const unsigned long long m = __ballot(pr != 0);
    const int wl = __popcll(m & ((1ull << lane) - 1ull));
    if (lane == 0) wt[w] = __popcll(m);
    __syncthreads();
    int wbase = 0;
    #pragma unroll
    for (int j = 0; j < 4; j++) if (j < w) wbase += wt[j];
    if (pr) {
      const int pos = base + wbase + wl;
      listT[e * NTOK + pos] = t;
      listW[e * NTOK + pos] = (pr == 1) ? topW[2 * t] : topW[2 * t + 1];
      listP[e * NTOK + pos] = pr;
    }
    base += wt[0] + wt[1] + wt[2] + wt[3];
    __syncthreads();
  }
  if (tid == 0) cnt[e] = base;
}

// ---------- tile map + slot arrays + inverse token->slot map ----------
__global__ __launch_bounds__(256) void k_tilemap(const int* __restrict__ cnt,
                                                 const int* __restrict__ listT,
                                                 const float* __restrict__ listW,
                                                 const int* __restrict__ listP,
                                                 int* __restrict__ tileExp,
                                                 int* __restrict__ tileM0,
                                                 int* __restrict__ slotTok,
                                                 float* __restrict__ slotW,
                                                 int* __restrict__ tokSlot) {
  __shared__ int offPad[NEXP + 1];
  __shared__ int cs[NEXP];
  const int tid = threadIdx.x;
  if (tid == 0) {
    int tt = 0, acc = 0;
    for (int e = 0; e < NEXP; e++) {
      cs[e] = cnt[e];
      offPad[e] = acc;
      const int tiles = (cs[e] + 127) >> 7;
      for (int i = 0; i < tiles; i++) { tileExp[tt] = e; tileM0[tt] = acc + i * 128; tt++; }
      acc += tiles * 128;
    }
    offPad[NEXP] = acc;
    for (int i = 0; i < NTOK / 128; i++) { tileExp[tt] = NEXP; tileM0[tt] = SHB + i * 128; tt++; }
    for (; tt < MAXT; tt++) tileExp[tt] = -1;
  }
  __syncthreads();
  for (int s = tid; s < CAPR; s += 256) {
    int tok = 0; float wv = 0.f; int pp = 0;
    #pragma unroll
    for (int e = 0; e < NEXP; e++)
      if (s >= offPad[e] && s < offPad[e + 1]) {
        const int i = s - offPad[e];
        if (i < cs[e]) {
          tok = listT[e * NTOK + i];
          wv = listW[e * NTOK + i];
          pp = listP[e * NTOK + i];
        }
      }
    slotTok[s] = tok; slotW[s] = wv;
    if (pp) tokSlot[2 * tok + (pp - 1)] = s;   // deterministic: unique (tok,pp)
  }
  for (int s = tid; s < NTOK; s += 256) { slotTok[SHB + s] = s; slotW[SHB + s] = 1.f; }
}

// ---------- gemm1: persistent 512 blocks, 128x128, 3-buf single-barrier pipeline ----------
__global__ __launch_bounds__(256, 2) void k_gemm1(const u16* __restrict__ xb,
                                                  const u16* __restrict__ w1t,
                                                  const u16* __restrict__ w2t,
                                                  const int* __restrict__ tileExp,
                                                  const int* __restrict__ tileM0,
                                                  const int* __restrict__ slotTok,
                                                  const float* __restrict__ slotW,
                                                  u16* __restrict__ hidden) {
  __shared__ alignas(16) u16 As[3][4096];
  __shared__ alignas(16) u16 B1s[3][4096];
  __shared__ alignas(16) u16 B2s[3][4096];
  constexpr size_t SL = (size_t)HID * DIM;
  const int tid = threadIdx.x, w = tid >> 6, lane = tid & 63;
  const int wr = w >> 1, wc = w & 1;
  const int c0 = w * 128 + lane, c1 = c0 + 64;       // chunk = kslot*128 + row
  const int l0 = c0 * 8, l1 = c1 * 8;
  const int aoff = ((lane >> 4) * 128 + wr * 64 + (lane & 15)) * 8;
  const int boff = ((lane >> 4) * 128 + wc * 64 + (lane & 15)) * 8;
  // XCD-chunked persistent id: 512 = 8 XCDs x 64
  const int sbid = ((int)blockIdx.x & 7) * 64 + ((int)blockIdx.x >> 3);

  for (int u = sbid; u < MAXT * (HID / 128); u += 512) {
    const int bx = u % MAXT, by = u / MAXT;          // M-fastest: neighbors share B panel
    const int e = tileExp[bx];
    if (e < 0) continue;
    const int m0 = tileM0[bx];
    const int nBase = by * 128;
    const u16* w1 = w1t + (size_t)e * SL;
    const u16* w2 = w2t + (size_t)e * SL;
    const int tok0 = slotTok[m0 + lane];             // c0&127 == lane
    const int tok1 = slotTok[m0 + 64 + lane];        // c1&127 == lane+64
    const u16* gA0 = xb + (size_t)tok0 * DIM + w * 8;
    const u16* gA1 = xb + (size_t)tok1 * DIM + w * 8;
    const u16* gB1a = w1 + (size_t)(nBase + lane) * DIM + w * 8;
    const u16* gB1b = w1 + (size_t)(nBase + 64 + lane) * DIM + w * 8;
    const u16* gB2a = w2 + (size_t)(nBase + lane) * DIM + w * 8;
    const u16* gB2b = w2 + (size_t)(nBase + 64 + lane) * DIM + w * 8;

    f32x4 acc1[4][4], acc2[4][4];
    const f32x4 vz = {0.f, 0.f, 0.f, 0.f};
    #pragma unroll
    for (int m = 0; m < 4; m++)
      #pragma unroll
      for (int n = 0; n < 4; n++) { acc1[m][n] = vz; acc2[m][n] = vz; }

#define G1_STAGE(buf, kk) do {                                                \
    GLDS16(gA0  + (kk), &As[buf][l0]);  GLDS16(gA1  + (kk), &As[buf][l1]);    \
    GLDS16(gB1a + (kk), &B1s[buf][l0]); GLDS16(gB1b + (kk), &B1s[buf][l1]);   \
    GLDS16(gB2a + (kk), &B2s[buf][l0]); GLDS16(gB2b + (kk), &B2s[buf][l1]);   \
  } while (0)

// single barrier per K-step; stage (buf+2)%3 issued right after barrier
#define G1_BODY(buf, vm, dostage, kk) do {                                    \
    SCHED(); VMCNT(vm); SBAR(); SCHED();                                      \
    if (dostage) { G1_STAGE((buf + 2) % 3, kk); SCHED(); }                    \
    bf16x8 av[4], b1v[4], b2v[4];                                             \
    _Pragma("unroll")                                                         \
    for (int m = 0; m < 4; m++) av[m] = *(const bf16x8*)&As[buf][aoff + m * 128]; \
    _Pragma("unroll")                                                         \
    for (int n = 0; n < 4; n++) {                                             \
      b1v[n] = *(const bf16x8*)&B1s[buf][boff + n * 128];                     \
      b2v[n] = *(const bf16x8*)&B2s[buf][boff + n * 128];                     \
    }                                                                         \
    __builtin_amdgcn_s_setprio(1);                                            \
    _Pragma("unroll")                                                         \
    for (int m = 0; m < 4; m++)                                               \
      _Pragma("unroll")                                                       \
      for (int n = 0; n < 4; n++) {                                           \
        acc1[m][n] = __builtin_amdgcn_mfma_f32_16x16x32_bf16(av[m], b1v[n], acc1[m][n], 0, 0, 0); \
        acc2[m][n] = __builtin_amdgcn_mfma_f32_16x16x32_bf16(av[m], b2v[n], acc2[m][n], 0, 0, 0); \
      }                                                                       \
    __builtin_amdgcn_s_setprio(0);                                            \
  } while (0)

    // 24 bodies; stage-ahead-2; 6 loads/stage -> steady VMCNT(6)
    G1_STAGE(0, 0);  SCHED();
    G1_STAGE(1, 32); SCHED();
    for (int t = 0; t < 21; t += 3) {
      G1_BODY(0, 6, true, (t + 2) * 32);
      G1_BODY(1, 6, true, (t + 3) * 32);
      G1_BODY(2, 6, true, (t + 4) * 32);
    }
    G1_BODY(0, 6, true, 23 * 32);
    G1_BODY(1, 6, false, 0);
    G1_BODY(2, 0, false, 0);
#undef G1_BODY
#undef G1_STAGE

    #pragma unroll
    for (int m = 0; m < 4; m++)
      #pragma unroll
      for (int r = 0; r < 4; r++) {
        const int slot = m0 + wr * 64 + m * 16 + (lane >> 4) * 4 + r;
        const float cwv = slotW[slot];
        #pragma unroll
        for (int n = 0; n < 4; n++) {
          const int hcol = nBase + wc * 64 + n * 16 + (lane & 15);
          const float v1 = acc1[m][n][r], v2 = acc2[m][n][r];
          hidden[(size_t)slot * HID + hcol] = f2bf((v1 / (1.f + __expf(-v1))) * v2 * cwv);
        }
      }
  }
}

// ---------- gemm2: 624 blocks (all-resident @3/CU), 3-buf single-barrier pipeline ----------
__global__ __launch_bounds__(256, 3) void k_gemm2(const u16* __restrict__ hid,
                                                  const u16* __restrict__ pjt,
                                                  const int* __restrict__ tileExp,
                                                  const int* __restrict__ tileM0,
                                                  float* __restrict__ g2) {
  __shared__ alignas(16) u16 As[3][4096];
  __shared__ alignas(16) u16 Bs[3][4096];
  const int chunk = (MAXT * (DIM / 128)) >> 3;   // 624/8 = 78
  const int bid = blockIdx.x;
  const int wgid = (bid & 7) * chunk + (bid >> 3);
  const int bx = wgid % MAXT;
  const int by = wgid / MAXT;
  const int e = tileExp[bx];
  if (e < 0) return;
  const int m0 = tileM0[bx];
  const int nBase = by * 128;
  constexpr size_t SL = (size_t)HID * DIM;
  const u16* pj = pjt + (size_t)e * SL;
  const int tid = threadIdx.x, w = tid >> 6, lane = tid & 63;
  const int wr = w >> 1, wc = w & 1;

  const int c0 = w * 128 + lane, c1 = c0 + 64;
  const u16* gA0 = hid + (size_t)(m0 + lane) * HID + w * 8;
  const u16* gA1 = hid + (size_t)(m0 + 64 + lane) * HID + w * 8;
  const u16* gBa = pj + (size_t)(nBase + lane) * HID + w * 8;
  const u16* gBb = pj + (size_t)(nBase + 64 + lane) * HID + w * 8;
  const int l0 = c0 * 8, l1 = c1 * 8;

  f32x4 acc[4][4];
  const f32x4 vz = {0.f, 0.f, 0.f, 0.f};
  #pragma unroll
  for (int m = 0; m < 4; m++)
    #pragma unroll
    for (int n = 0; n < 4; n++) acc[m][n] = vz;

  const int aoff = ((lane >> 4) * 128 + wr * 64 + (lane & 15)) * 8;
  const int boff = ((lane >> 4) * 128 + wc * 64 + (lane & 15)) * 8;

#define G2_STAGE(buf, kk) do {                                                \
    GLDS16(gA0 + (kk), &As[buf][l0]); GLDS16(gA1 + (kk), &As[buf][l1]);       \
    GLDS16(gBa + (kk), &Bs[buf][l0]); GLDS16(gBb + (kk), &Bs[buf][l1]);       \
  } while (0)

#define G2_BODY(buf, vm, dostage, kk) do {                                    \
    SCHED(); VMCNT(vm); SBAR(); SCHED();                                      \
    if (dostage) { G2_STAGE((buf + 2) % 3, kk); SCHED(); }                    \
    bf16x8 av[4], bv[4];                                                      \
    _Pragma("unroll")                                                         \
    for (int m = 0; m < 4; m++) av[m] = *(const bf16x8*)&As[buf][aoff + m * 128]; \
    _Pragma("unroll")                                                         \
    for (int n = 0; n < 4; n++) bv[n] = *(const bf16x8*)&Bs[buf][boff + n * 128]; \
    __builtin_amdgcn_s_setprio(1);                                            \
    _Pragma("unroll")                                                         \
    for (int m = 0; m < 4; m++)                                               \
      _Pragma("unroll")                                                       \
      for (int n = 0; n < 4; n++)                                             \
        acc[m][n] = __builtin_amdgcn_mfma_f32_16x16x32_bf16(av[m], bv[n], acc[m][n], 0, 0, 0); \
    __builtin_amdgcn_s_setprio(0);                                            \
  } while (0)

  // 48 bodies; stage-ahead-2; 4 loads/stage -> steady VMCNT(4)
  G2_STAGE(0, 0);  SCHED();
  G2_STAGE(1, 32); SCHED();
  for (int t = 0; t < 45; t += 3) {
    G2_BODY(0, 4, true, (t + 2) * 32);
    G2_BODY(1, 4, true, (t + 3) * 32);
    G2_BODY(2, 4, true, (t + 4) * 32);
  }
  G2_BODY(0, 4, true, 47 * 32);
  G2_BODY(1, 4, false, 0);
  G2_BODY(2, 0, false, 0);
#undef G2_BODY
#undef G2_STAGE

  #pragma unroll
  for (int m = 0; m < 4; m++)
    #pragma unroll
    for (int r = 0; r < 4; r++) {
      const int slot = m0 + wr * 64 + m * 16 + (lane >> 4) * 4 + r;
      #pragma unroll
      for (int n = 0; n < 4; n++) {
        const int dcol = nBase + wc * 64 + n * 16 + (lane & 15);
        g2[(size_t)slot * DIM + dcol] = acc[m][n][r];
      }
    }
}

// ---------- combine: out[t] = g2[minSlot] + g2[maxSlot] + g2[shared]  (deterministic) ----------
__global__ __launch_bounds__(192) void k_combine(const float* __restrict__ g2,
                                                 const int* __restrict__ tokSlot,
                                                 float* __restrict__ out) {
  const int t = blockIdx.x, d4 = threadIdx.x;
  const int sA = tokSlot[2 * t], sB = tokSlot[2 * t + 1];
  const int lo = sA < sB ? sA : sB;
  const int hi = sA < sB ? sB : sA;
  const float4 a = ((const float4*)(g2 + (size_t)lo * DIM))[d4];
  const float4 b = ((const float4*)(g2 + (size_t)hi * DIM))[d4];
  const float4 c = ((const float4*)(g2 + (size_t)(SHB + t) * DIM))[d4];
  float4 o;
  o.x = a.x + b.x + c.x; o.y = a.y + b.y + c.y;
  o.z = a.z + b.z + c.z; o.w = a.w + b.w + c.w;
  ((float4*)(out + (size_t)t * DIM))[d4] = o;
}

// ---------- launch ----------
extern "C" void kernel_launch(void* const* d_in, const int* in_sizes, int n_in,
                              void* d_out, int out_size, void* d_ws, size_t ws_size,
                              hipStream_t stream) {
  const float* x     = (const float*)d_in[0];
  const float* rw    = (const float*)d_in[1];
  const float* sw1   = (const float*)d_in[2];
  const float* sw2   = (const float*)d_in[3];
  const float* sproj = (const float*)d_in[4];
  const float* ew1   = (const float*)d_in[5];
  const float* ew2   = (const float*)d_in[6];
  const float* eproj = (const float*)d_in[7];
  float* out   = (float*)d_out;
  float* probs = out + (size_t)NTOK * DIM;

  constexpr size_t SL = (size_t)HID * DIM;
  constexpr size_t off_xb   = 0;
  constexpr size_t off_w1t  = 6291456;
  constexpr size_t off_w2t  = off_w1t + 2 * 9 * SL;
  constexpr size_t off_pjt  = off_w2t + 2 * 9 * SL;
  constexpr size_t off_hid  = off_pjt + 2 * 9 * SL;              // 69,992,448
  constexpr size_t off_g2   = off_hid + (size_t)NSLOT * HID * 2; // 110,886,912
  constexpr size_t off_meta = off_g2 + (size_t)NSLOT * DIM * 4;  // 151,781,376

  char* ws = (char*)d_ws;
  u16*   xb   = (u16*)(ws + off_xb);
  u16*   w1t  = (u16*)(ws + off_w1t);
  u16*   w2t  = (u16*)(ws + off_w2t);
  u16*   pjt  = (u16*)(ws + off_pjt);
  u16*   hid  = (u16*)(ws + off_hid);
  float* g2   = (float*)(ws + off_g2);
  char*  meta = ws + off_meta;
  int*   topIdx  = (int*)meta;                        // 32 KB
  float* topW    = (float*)(meta + 32768);            // 32 KB
  int*   listT   = (int*)(meta + 65536);              // 128 KB
  float* listW   = (float*)(meta + 196608);           // 128 KB
  int*   listP   = (int*)(meta + 327680);             // 128 KB
  int*   cnt     = (int*)(meta + 458752);
  int*   tileExp = (int*)(meta + 459264);
  int*   tileM0  = (int*)(meta + 459776);
  int*   slotTok = (int*)(meta + 460288);             // 52 KB
  float* slotW   = (float*)(meta + 513536);           // 52 KB
  int*   tokSlot = (int*)(meta + 566784);             // 32 KB

  k_cvt_x<<<(NTOK * DIM / 4 + 255) / 256, 256, 0, stream>>>(x, xb, NTOK * DIM / 4);
  k_tr_all<<<dim3(HID / 32, DIM / 32, 27), dim3(32, 8), 0, stream>>>(
      ew1, sw1, ew2, sw2, eproj, sproj, w1t);

  k_router<<<NTOK, 64, 0, stream>>>(x, rw, probs, topIdx, topW);
  k_build<<<NEXP, 256, 0, stream>>>(topIdx, topW, listT, listW, listP, cnt);
  k_tilemap<<<1, 256, 0, stream>>>(cnt, listT, listW, listP, tileExp, tileM0,
                                   slotTok, slotW, tokSlot);

  k_gemm1<<<512, 256, 0, stream>>>(xb, w1t, w2t, tileExp, tileM0,
                                   slotTok, slotW, hid);
  k_gemm2<<<MAXT * (DIM / 128), 256, 0, stream>>>(hid, pjt, tileExp, tileM0, g2);
  k_combine<<<NTOK, 192, 0, stream>>>(g2, tokSlot, out);
}

// Round 6
// 291.290 us; speedup vs baseline: 1.0687x; 1.0687x over previous
//
#include <hip/hip_runtime.h>

typedef unsigned short u16;
typedef __bf16 bf16x8 __attribute__((ext_vector_type(8)));
typedef float f32x4 __attribute__((ext_vector_type(4)));

// ---------- helpers ----------
__device__ __forceinline__ u16 f2bf(float f) {
  union { float f; unsigned u; } v; v.f = f;
  return (u16)((v.u + 0x7fffu + ((v.u >> 16) & 1u)) >> 16);   // RNE
}

#define GLDS16(g, l)                                                          \
  __builtin_amdgcn_global_load_lds(                                           \
      (const __attribute__((address_space(1))) void*)(g),                     \
      (__attribute__((address_space(3))) void*)(l), 16, 0, 0)

#define SBAR()  __builtin_amdgcn_s_barrier()
#define SCHED() __builtin_amdgcn_sched_barrier(0)
#define VMCNT(n) asm volatile("s_waitcnt vmcnt(" #n ")" ::: "memory")

// ---------- sizes ----------
#define NTOK 4096     // B*T
#define DIM  768
#define HID  1536
#define NEXP 8
#define CAPR 9216     // routed slot capacity (8192 + per-expert pad to 128)
#define SHB  9216     // shared-expert slot base
#define NSLOT 13312   // CAPR + NTOK
#define MAXT 104      // max M-tiles: <=72 routed + 32 shared

// ---------- fused transpose: 27 slices f32[R][C] -> bf16[C][R], 64x64 tiles ----------
// reads 256B-coalesced, writes 128B-coalesced
__global__ __launch_bounds__(256) void k_tr_all(const float* __restrict__ ew1,
                                                const float* __restrict__ sw1,
                                                const float* __restrict__ ew2,
                                                const float* __restrict__ sw2,
                                                const float* __restrict__ eproj,
                                                const float* __restrict__ sproj,
                                                u16* __restrict__ dstBase) {
  __shared__ u16 tile[64][65];
  constexpr size_t SL = (size_t)HID * DIM;
  const int z = blockIdx.z;
  const float* src;
  int R, C, bxx = blockIdx.x, byy = blockIdx.y;
  if (z < 9)       { src = (z < 8) ? ew1 + (size_t)z * SL : sw1; R = DIM; C = HID; }
  else if (z < 18) { const int q = z - 9;  src = (q < 8) ? ew2 + (size_t)q * SL : sw2; R = DIM; C = HID; }
  else             { const int q = z - 18; src = (q < 8) ? eproj + (size_t)q * SL : sproj;
                     R = HID; C = DIM; const int t = bxx; bxx = byy; byy = t; }
  u16* dst = dstBase + (size_t)z * SL;
  const int c0 = bxx * 64, r0 = byy * 64;
  const int tx = threadIdx.x, ty = threadIdx.y;   // (64,4)
  #pragma unroll
  for (int i = 0; i < 16; i++)
    tile[ty + 4 * i][tx] = f2bf(src[(size_t)(r0 + ty + 4 * i) * C + c0 + tx]);
  __syncthreads();
  #pragma unroll
  for (int i = 0; i < 16; i++)
    dst[(size_t)(c0 + ty + 4 * i) * R + r0 + tx] = tile[tx][ty + 4 * i];
}

// ---------- router: probs + top-2 (renormalized) + x->bf16 ----------
__global__ __launch_bounds__(64) void k_router(const float* __restrict__ x,
                                               const float* __restrict__ rw,
                                               float* __restrict__ probs,
                                               int* __restrict__ topIdx,
                                               float* __restrict__ topW,
                                               u16* __restrict__ xb) {
  const int t = blockIdx.x;
  const int lane = threadIdx.x;
  const float* xr = x + (size_t)t * DIM;
  u16* xbr = xb + (size_t)t * DIM;
  float acc[NEXP] = {0, 0, 0, 0, 0, 0, 0, 0};
  #pragma unroll
  for (int i = 0; i < DIM / 64; i++) {
    const int d = lane + 64 * i;
    const float xv = xr[d];
    xbr[d] = f2bf(xv);
    #pragma unroll
    for (int e = 0; e < NEXP; e++) acc[e] += xv * rw[e * DIM + d];
  }
  #pragma unroll
  for (int e = 0; e < NEXP; e++)
    #pragma unroll
    for (int s = 32; s > 0; s >>= 1) acc[e] += __shfl_xor(acc[e], s, 64);
  if (lane == 0) {
    float mx = acc[0];
    #pragma unroll
    for (int e = 1; e < NEXP; e++) mx = fmaxf(mx, acc[e]);
    float p[NEXP], sum = 0.f;
    #pragma unroll
    for (int e = 0; e < NEXP; e++) { p[e] = expf(acc[e] - mx); sum += p[e]; }
    const float inv = 1.f / sum;
    #pragma unroll
    for (int e = 0; e < NEXP; e++) p[e] *= inv;
    #pragma unroll
    for (int e = 0; e < NEXP; e++) probs[(size_t)t * NEXP + e] = p[e];
    int i1 = 0;
    #pragma unroll
    for (int e = 1; e < NEXP; e++) if (p[e] > p[i1]) i1 = e;
    int i2 = (i1 == 0) ? 1 : 0;
    #pragma unroll
    for (int e = 0; e < NEXP; e++) if (e != i1 && p[e] > p[i2]) i2 = e;
    const float s2 = 1.f / (p[i1] + p[i2]);
    topIdx[2 * t] = i1; topIdx[2 * t + 1] = i2;
    topW[2 * t] = p[i1] * s2; topW[2 * t + 1] = p[i2] * s2;
  }
}

// ---------- per-expert stable compaction (one block per expert) ----------
__global__ __launch_bounds__(256) void k_build(const int* __restrict__ topIdx,
                                               const float* __restrict__ topW,
                                               int* __restrict__ listT,
                                               float* __restrict__ listW,
                                               int* __restrict__ listP,
                                               int* __restrict__ cnt) {
  const int e = blockIdx.x;
  const int tid = threadIdx.x, w = tid >> 6, lane = tid & 63;
  __shared__ int wt[4];
  int base = 0;
  for (int c = 0; c < NTOK / 256; ++c) {
    const int t = c * 256 + tid;
    const int i0 = topIdx[2 * t], i1 = topIdx[2 * t + 1];
    const int pr = (i0 == e) ? 1 : ((i1 == e) ? 2 : 0);
    const unsigned long long m = __ballot(pr != 0);
    const int wl = __popcll(m & ((1ull << lane) - 1ull));
    if (lane == 0) wt[w] = __popcll(m);
    __syncthreads();
    int wbase = 0;
    #pragma unroll
    for (int j = 0; j < 4; j++) if (j < w) wbase += wt[j];
    if (pr) {
      const int pos = base + wbase + wl;
      listT[e * NTOK + pos] = t;
      listW[e * NTOK + pos] = (pr == 1) ? topW[2 * t] : topW[2 * t + 1];
      listP[e * NTOK + pos] = pr;
    }
    base += wt[0] + wt[1] + wt[2] + wt[3];
    __syncthreads();
  }
  if (tid == 0) cnt[e] = base;
}

// ---------- tile map + slot arrays + inverse token->slot map ----------
__global__ __launch_bounds__(256) void k_tilemap(const int* __restrict__ cnt,
                                                 const int* __restrict__ listT,
                                                 const float* __restrict__ listW,
                                                 const int* __restrict__ listP,
                                                 int* __restrict__ tileExp,
                                                 int* __restrict__ tileM0,
                                                 int* __restrict__ slotTok,
                                                 float* __restrict__ slotW,
                                                 int* __restrict__ tokSlot) {
  __shared__ int offPad[NEXP + 1];
  __shared__ int cs[NEXP];
  const int tid = threadIdx.x;
  if (tid == 0) {
    int tt = 0, acc = 0;
    for (int e = 0; e < NEXP; e++) {
      cs[e] = cnt[e];
      offPad[e] = acc;
      const int tiles = (cs[e] + 127) >> 7;
      for (int i = 0; i < tiles; i++) { tileExp[tt] = e; tileM0[tt] = acc + i * 128; tt++; }
      acc += tiles * 128;
    }
    offPad[NEXP] = acc;
    for (int i = 0; i < NTOK / 128; i++) { tileExp[tt] = NEXP; tileM0[tt] = SHB + i * 128; tt++; }
    for (; tt < MAXT; tt++) tileExp[tt] = -1;
  }
  __syncthreads();
  for (int s = tid; s < CAPR; s += 256) {
    int tok = 0; float wv = 0.f; int pp = 0;
    #pragma unroll
    for (int e = 0; e < NEXP; e++)
      if (s >= offPad[e] && s < offPad[e + 1]) {
        const int i = s - offPad[e];
        if (i < cs[e]) {
          tok = listT[e * NTOK + i];
          wv = listW[e * NTOK + i];
          pp = listP[e * NTOK + i];
        }
      }
    slotTok[s] = tok; slotW[s] = wv;
    if (pp) tokSlot[2 * tok + (pp - 1)] = s;   // deterministic: unique (tok,pp)
  }
  for (int s = tid; s < NTOK; s += 256) { slotTok[SHB + s] = s; slotW[SHB + s] = 1.f; }
}

// ---------- gemm1: 1248 blocks (XCD-chunked), 128x128, 3-buf single-barrier pipeline ----------
__global__ __launch_bounds__(256, 2) void k_gemm1(const u16* __restrict__ xb,
                                                  const u16* __restrict__ w1t,
                                                  const u16* __restrict__ w2t,
                                                  const int* __restrict__ tileExp,
                                                  const int* __restrict__ tileM0,
                                                  const int* __restrict__ slotTok,
                                                  const float* __restrict__ slotW,
                                                  u16* __restrict__ hidden) {
  __shared__ alignas(16) u16 As[3][4096];
  __shared__ alignas(16) u16 B1s[3][4096];
  __shared__ alignas(16) u16 B2s[3][4096];
  // XCD-chunked bijective swizzle (nwg = 1248 = 8*156), M-tile-fastest order
  const int chunk = (MAXT * (HID / 128)) >> 3;
  const int bid = blockIdx.x;
  const int wgid = (bid & 7) * chunk + (bid >> 3);
  const int bx = wgid % MAXT;
  const int by = wgid / MAXT;
  const int e = tileExp[bx];
  if (e < 0) return;
  const int m0 = tileM0[bx];
  const int nBase = by * 128;
  constexpr size_t SL = (size_t)HID * DIM;
  const u16* w1 = w1t + (size_t)e * SL;
  const u16* w2 = w2t + (size_t)e * SL;
  const int tid = threadIdx.x, w = tid >> 6, lane = tid & 63;
  const int wr = w >> 1, wc = w & 1;

  // staging chunks: c = kslot*128 + row; per-wave contiguous (uniform + lane*16B)
  const int c0 = w * 128 + lane, c1 = c0 + 64;
  const int tok0 = slotTok[m0 + lane];
  const int tok1 = slotTok[m0 + 64 + lane];
  const u16* gA0 = xb + (size_t)tok0 * DIM + w * 8;
  const u16* gA1 = xb + (size_t)tok1 * DIM + w * 8;
  const u16* gB1a = w1 + (size_t)(nBase + lane) * DIM + w * 8;
  const u16* gB1b = w1 + (size_t)(nBase + 64 + lane) * DIM + w * 8;
  const u16* gB2a = w2 + (size_t)(nBase + lane) * DIM + w * 8;
  const u16* gB2b = w2 + (size_t)(nBase + 64 + lane) * DIM + w * 8;
  const int l0 = c0 * 8, l1 = c1 * 8;

  f32x4 acc1[4][4], acc2[4][4];
  const f32x4 vz = {0.f, 0.f, 0.f, 0.f};
  #pragma unroll
  for (int m = 0; m < 4; m++)
    #pragma unroll
    for (int n = 0; n < 4; n++) { acc1[m][n] = vz; acc2[m][n] = vz; }

  const int aoff = ((lane >> 4) * 128 + wr * 64 + (lane & 15)) * 8;
  const int boff = ((lane >> 4) * 128 + wc * 64 + (lane & 15)) * 8;

#define G1_STAGE(buf, kk) do {                                                \
    GLDS16(gA0  + (kk), &As[buf][l0]);  GLDS16(gA1  + (kk), &As[buf][l1]);    \
    GLDS16(gB1a + (kk), &B1s[buf][l0]); GLDS16(gB1b + (kk), &B1s[buf][l1]);   \
    GLDS16(gB2a + (kk), &B2s[buf][l0]); GLDS16(gB2b + (kk), &B2s[buf][l1]);   \
  } while (0)

// single barrier per K-step; stage (buf+2)%3 issued right after barrier
#define G1_BODY(buf, vm, dostage, kk) do {                                    \
    SCHED(); VMCNT(vm); SBAR(); SCHED();                                      \
    if (dostage) { G1_STAGE((buf + 2) % 3, kk); SCHED(); }                    \
    bf16x8 av[4], b1v[4], b2v[4];                                             \
    _Pragma("unroll")                                                         \
    for (int m = 0; m < 4; m++) av[m] = *(const bf16x8*)&As[buf][aoff + m * 128]; \
    _Pragma("unroll")                                                         \
    for (int n = 0; n < 4; n++) {                                             \
      b1v[n] = *(const bf16x8*)&B1s[buf][boff + n * 128];                     \
      b2v[n] = *(const bf16x8*)&B2s[buf][boff + n * 128];                     \
    }                                                                         \
    __builtin_amdgcn_s_setprio(1);                                            \
    _Pragma("unroll")                                                         \
    for (int m = 0; m < 4; m++)                                               \
      _Pragma("unroll")                                                       \
      for (int n = 0; n < 4; n++) {                                           \
        acc1[m][n] = __builtin_amdgcn_mfma_f32_16x16x32_bf16(av[m], b1v[n], acc1[m][n], 0, 0, 0); \
        acc2[m][n] = __builtin_amdgcn_mfma_f32_16x16x32_bf16(av[m], b2v[n], acc2[m][n], 0, 0, 0); \
      }                                                                       \
    __builtin_amdgcn_s_setprio(0);                                            \
  } while (0)

  // 24 bodies; stage-ahead-2; 6 loads/stage -> steady VMCNT(6)
  G1_STAGE(0, 0);  SCHED();
  G1_STAGE(1, 32); SCHED();
  for (int t = 0; t < 21; t += 3) {
    G1_BODY(0, 6, true, (t + 2) * 32);
    G1_BODY(1, 6, true, (t + 3) * 32);
    G1_BODY(2, 6, true, (t + 4) * 32);
  }
  G1_BODY(0, 6, true, 23 * 32);
  G1_BODY(1, 6, false, 0);
  G1_BODY(2, 0, false, 0);
#undef G1_BODY
#undef G1_STAGE

  #pragma unroll
  for (int m = 0; m < 4; m++)
    #pragma unroll
    for (int r = 0; r < 4; r++) {
      const int slot = m0 + wr * 64 + m * 16 + (lane >> 4) * 4 + r;
      const float cwv = slotW[slot];
      #pragma unroll
      for (int n = 0; n < 4; n++) {
        const int hcol = nBase + wc * 64 + n * 16 + (lane & 15);
        const float v1 = acc1[m][n][r], v2 = acc2[m][n][r];
        hidden[(size_t)slot * HID + hcol] = f2bf((v1 / (1.f + __expf(-v1))) * v2 * cwv);
      }
    }
}

// ---------- gemm2: 624 blocks (all-resident @3/CU), 3-buf single-barrier pipeline ----------
__global__ __launch_bounds__(256, 3) void k_gemm2(const u16* __restrict__ hid,
                                                  const u16* __restrict__ pjt,
                                                  const int* __restrict__ tileExp,
                                                  const int* __restrict__ tileM0,
                                                  float* __restrict__ g2) {
  __shared__ alignas(16) u16 As[3][4096];
  __shared__ alignas(16) u16 Bs[3][4096];
  const int chunk = (MAXT * (DIM / 128)) >> 3;   // 624/8 = 78
  const int bid = blockIdx.x;
  const int wgid = (bid & 7) * chunk + (bid >> 3);
  const int bx = wgid % MAXT;
  const int by = wgid / MAXT;
  const int e = tileExp[bx];
  if (e < 0) return;
  const int m0 = tileM0[bx];
  const int nBase = by * 128;
  constexpr size_t SL = (size_t)HID * DIM;
  const u16* pj = pjt + (size_t)e * SL;
  const int tid = threadIdx.x, w = tid >> 6, lane = tid & 63;
  const int wr = w >> 1, wc = w & 1;

  const int c0 = w * 128 + lane, c1 = c0 + 64;
  const u16* gA0 = hid + (size_t)(m0 + lane) * HID + w * 8;
  const u16* gA1 = hid + (size_t)(m0 + 64 + lane) * HID + w * 8;
  const u16* gBa = pj + (size_t)(nBase + lane) * HID + w * 8;
  const u16* gBb = pj + (size_t)(nBase + 64 + lane) * HID + w * 8;
  const int l0 = c0 * 8, l1 = c1 * 8;

  f32x4 acc[4][4];
  const f32x4 vz = {0.f, 0.f, 0.f, 0.f};
  #pragma unroll
  for (int m = 0; m < 4; m++)
    #pragma unroll
    for (int n = 0; n < 4; n++) acc[m][n] = vz;

  const int aoff = ((lane >> 4) * 128 + wr * 64 + (lane & 15)) * 8;
  const int boff = ((lane >> 4) * 128 + wc * 64 + (lane & 15)) * 8;

#define G2_STAGE(buf, kk) do {                                                \
    GLDS16(gA0 + (kk), &As[buf][l0]); GLDS16(gA1 + (kk), &As[buf][l1]);       \
    GLDS16(gBa + (kk), &Bs[buf][l0]); GLDS16(gBb + (kk), &Bs[buf][l1]);       \
  } while (0)

#define G2_BODY(buf, vm, dostage, kk) do {                                    \
    SCHED(); VMCNT(vm); SBAR(); SCHED();                                      \
    if (dostage) { G2_STAGE((buf + 2) % 3, kk); SCHED(); }                    \
    bf16x8 av[4], bv[4];                                                      \
    _Pragma("unroll")                                                         \
    for (int m = 0; m < 4; m++) av[m] = *(const bf16x8*)&As[buf][aoff + m * 128]; \
    _Pragma("unroll")                                                         \
    for (int n = 0; n < 4; n++) bv[n] = *(const bf16x8*)&Bs[buf][boff + n * 128]; \
    __builtin_amdgcn_s_setprio(1);                                            \
    _Pragma("unroll")                                                         \
    for (int m = 0; m < 4; m++)                                               \
      _Pragma("unroll")                                                       \
      for (int n = 0; n < 4; n++)                                             \
        acc[m][n] = __builtin_amdgcn_mfma_f32_16x16x32_bf16(av[m], bv[n], acc[m][n], 0, 0, 0); \
    __builtin_amdgcn_s_setprio(0);                                            \
  } while (0)

  // 48 bodies; stage-ahead-2; 4 loads/stage -> steady VMCNT(4)
  G2_STAGE(0, 0);  SCHED();
  G2_STAGE(1, 32); SCHED();
  for (int t = 0; t < 45; t += 3) {
    G2_BODY(0, 4, true, (t + 2) * 32);
    G2_BODY(1, 4, true, (t + 3) * 32);
    G2_BODY(2, 4, true, (t + 4) * 32);
  }
  G2_BODY(0, 4, true, 47 * 32);
  G2_BODY(1, 4, false, 0);
  G2_BODY(2, 0, false, 0);
#undef G2_BODY
#undef G2_STAGE

  #pragma unroll
  for (int m = 0; m < 4; m++)
    #pragma unroll
    for (int r = 0; r < 4; r++) {
      const int slot = m0 + wr * 64 + m * 16 + (lane >> 4) * 4 + r;
      #pragma unroll
      for (int n = 0; n < 4; n++) {
        const int dcol = nBase + wc * 64 + n * 16 + (lane & 15);
        g2[(size_t)slot * DIM + dcol] = acc[m][n][r];
      }
    }
}

// ---------- combine: out[t] = g2[minSlot] + g2[maxSlot] + g2[shared]  (deterministic) ----------
__global__ __launch_bounds__(192) void k_combine(const float* __restrict__ g2,
                                                 const int* __restrict__ tokSlot,
                                                 float* __restrict__ out) {
  const int t = blockIdx.x, d4 = threadIdx.x;
  const int sA = tokSlot[2 * t], sB = tokSlot[2 * t + 1];
  const int lo = sA < sB ? sA : sB;
  const int hi = sA < sB ? sB : sA;
  const float4 a = ((const float4*)(g2 + (size_t)lo * DIM))[d4];
  const float4 b = ((const float4*)(g2 + (size_t)hi * DIM))[d4];
  const float4 c = ((const float4*)(g2 + (size_t)(SHB + t) * DIM))[d4];
  float4 o;
  o.x = a.x + b.x + c.x; o.y = a.y + b.y + c.y;
  o.z = a.z + b.z + c.z; o.w = a.w + b.w + c.w;
  ((float4*)(out + (size_t)t * DIM))[d4] = o;
}

// ---------- launch ----------
extern "C" void kernel_launch(void* const* d_in, const int* in_sizes, int n_in,
                              void* d_out, int out_size, void* d_ws, size_t ws_size,
                              hipStream_t stream) {
  const float* x     = (const float*)d_in[0];
  const float* rw    = (const float*)d_in[1];
  const float* sw1   = (const float*)d_in[2];
  const float* sw2   = (const float*)d_in[3];
  const float* sproj = (const float*)d_in[4];
  const float* ew1   = (const float*)d_in[5];
  const float* ew2   = (const float*)d_in[6];
  const float* eproj = (const float*)d_in[7];
  float* out   = (float*)d_out;
  float* probs = out + (size_t)NTOK * DIM;

  constexpr size_t SL = (size_t)HID * DIM;
  constexpr size_t off_xb   = 0;
  constexpr size_t off_w1t  = 6291456;
  constexpr size_t off_w2t  = off_w1t + 2 * 9 * SL;
  constexpr size_t off_pjt  = off_w2t + 2 * 9 * SL;
  constexpr size_t off_hid  = off_pjt + 2 * 9 * SL;              // 69,992,448
  constexpr size_t off_g2   = off_hid + (size_t)NSLOT * HID * 2; // 110,886,912
  constexpr size_t off_meta = off_g2 + (size_t)NSLOT * DIM * 4;  // 151,781,376

  char* ws = (char*)d_ws;
  u16*   xb   = (u16*)(ws + off_xb);
  u16*   w1t  = (u16*)(ws + off_w1t);
  u16*   w2t  = (u16*)(ws + off_w2t);
  u16*   pjt  = (u16*)(ws + off_pjt);
  u16*   hid  = (u16*)(ws + off_hid);
  float* g2   = (float*)(ws + off_g2);
  char*  meta = ws + off_meta;
  int*   topIdx  = (int*)meta;                        // 32 KB
  float* topW    = (float*)(meta + 32768);            // 32 KB
  int*   listT   = (int*)(meta + 65536);              // 128 KB
  float* listW   = (float*)(meta + 196608);           // 128 KB
  int*   listP   = (int*)(meta + 327680);             // 128 KB
  int*   cnt     = (int*)(meta + 458752);
  int*   tileExp = (int*)(meta + 459264);
  int*   tileM0  = (int*)(meta + 459776);
  int*   slotTok = (int*)(meta + 460288);             // 52 KB
  float* slotW   = (float*)(meta + 513536);           // 52 KB
  int*   tokSlot = (int*)(meta + 566784);             // 32 KB

  k_router<<<NTOK, 64, 0, stream>>>(x, rw, probs, topIdx, topW, xb);
  k_tr_all<<<dim3(HID / 64, DIM / 64, 27), dim3(64, 4), 0, stream>>>(
      ew1, sw1, ew2, sw2, eproj, sproj, w1t);

  k_build<<<NEXP, 256, 0, stream>>>(topIdx, topW, listT, listW, listP, cnt);
  k_tilemap<<<1, 256, 0, stream>>>(cnt, listT, listW, listP, tileExp, tileM0,
                                   slotTok, slotW, tokSlot);

  k_gemm1<<<MAXT * (HID / 128), 256, 0, stream>>>(xb, w1t, w2t, tileExp, tileM0,
                                                  slotTok, slotW, hid);
  k_gemm2<<<MAXT * (DIM / 128), 256, 0, stream>>>(hid, pjt, tileExp, tileM0, g2);
  k_combine<<<NTOK, 192, 0, stream>>>(g2, tokSlot, out);
}

// Round 7
// 223.976 us; speedup vs baseline: 1.3898x; 1.3005x over previous
//
#include <hip/hip_runtime.h>

typedef unsigned short u16;
typedef __bf16 bf16x8 __attribute__((ext_vector_type(8)));
typedef float f32x4 __attribute__((ext_vector_type(4)));

// ---------- helpers ----------
__device__ __forceinline__ u16 f2bf(float f) {
  union { float f; unsigned u; } v; v.f = f;
  return (u16)((v.u + 0x7fffu + ((v.u >> 16) & 1u)) >> 16);   // RNE
}

#define GLDS16(g, l)                                                          \
  __builtin_amdgcn_global_load_lds(                                           \
      (const __attribute__((address_space(1))) void*)(g),                     \
      (__attribute__((address_space(3))) void*)(l), 16, 0, 0)

#define SBAR()  __builtin_amdgcn_s_barrier()
#define SCHED() __builtin_amdgcn_sched_barrier(0)
#define VMCNT(n) asm volatile("s_waitcnt vmcnt(" #n ")" ::: "memory")

// ---------- sizes ----------
#define NTOK 4096     // B*T
#define DIM  768
#define HID  1536
#define NEXP 8
#define CAPR 9216     // routed slot capacity (8192 + per-expert pad to 128)
#define SHB  9216     // shared-expert slot base
#define NSLOT 13312   // CAPR + NTOK
#define MAXT 104      // max M-tiles: <=72 routed + 32 shared

// LDS tile chunk map (both GEMMs): 128 rows x 32 k-elems, 16B chunks.
//   chunk c = row*4 + (kslot ^ ((row>>1)&3)),  LDS u16 offset = c*8
// Stage side: wave w, load j, lane l -> c=(2w+j)*64+l:
//   row = (2w+j)*16 + (l>>2), kslot = (l&3)^((l>>3)&3)
//   => 4-lane groups read one full 64B line (coalesced, permuted-in-line).
// Read side: row r, kslot K -> u16 off = r*32 + (K ^ ((r>>1)&3))*8; the XOR
//   term is invariant under r += 16/64 so it folds into a per-thread const.

// ---------- fused transpose: 27 slices f32[R][C] -> bf16[C][R], 64x64 tiles ----------
__global__ __launch_bounds__(256) void k_tr_all(const float* __restrict__ ew1,
                                                const float* __restrict__ sw1,
                                                const float* __restrict__ ew2,
                                                const float* __restrict__ sw2,
                                                const float* __restrict__ eproj,
                                                const float* __restrict__ sproj,
                                                u16* __restrict__ dstBase) {
  __shared__ u16 tile[64][65];
  constexpr size_t SL = (size_t)HID * DIM;
  const int z = blockIdx.z;
  const float* src;
  int R, C, bxx = blockIdx.x, byy = blockIdx.y;
  if (z < 9)       { src = (z < 8) ? ew1 + (size_t)z * SL : sw1; R = DIM; C = HID; }
  else if (z < 18) { const int q = z - 9;  src = (q < 8) ? ew2 + (size_t)q * SL : sw2; R = DIM; C = HID; }
  else             { const int q = z - 18; src = (q < 8) ? eproj + (size_t)q * SL : sproj;
                     R = HID; C = DIM; const int t = bxx; bxx = byy; byy = t; }
  u16* dst = dstBase + (size_t)z * SL;
  const int c0 = bxx * 64, r0 = byy * 64;
  const int tx = threadIdx.x, ty = threadIdx.y;   // (64,4)
  #pragma unroll
  for (int i = 0; i < 16; i++)
    tile[ty + 4 * i][tx] = f2bf(src[(size_t)(r0 + ty + 4 * i) * C + c0 + tx]);
  __syncthreads();
  #pragma unroll
  for (int i = 0; i < 16; i++)
    dst[(size_t)(c0 + ty + 4 * i) * R + r0 + tx] = tile[tx][ty + 4 * i];
}

// ---------- router: probs + top-2 (renormalized) + x->bf16 ----------
__global__ __launch_bounds__(64) void k_router(const float* __restrict__ x,
                                               const float* __restrict__ rw,
                                               float* __restrict__ probs,
                                               int* __restrict__ topIdx,
                                               float* __restrict__ topW,
                                               u16* __restrict__ xb) {
  const int t = blockIdx.x;
  const int lane = threadIdx.x;
  const float* xr = x + (size_t)t * DIM;
  u16* xbr = xb + (size_t)t * DIM;
  float acc[NEXP] = {0, 0, 0, 0, 0, 0, 0, 0};
  #pragma unroll
  for (int i = 0; i < DIM / 64; i++) {
    const int d = lane + 64 * i;
    const float xv = xr[d];
    xbr[d] = f2bf(xv);
    #pragma unroll
    for (int e = 0; e < NEXP; e++) acc[e] += xv * rw[e * DIM + d];
  }
  #pragma unroll
  for (int e = 0; e < NEXP; e++)
    #pragma unroll
    for (int s = 32; s > 0; s >>= 1) acc[e] += __shfl_xor(acc[e], s, 64);
  if (lane == 0) {
    float mx = acc[0];
    #pragma unroll
    for (int e = 1; e < NEXP; e++) mx = fmaxf(mx, acc[e]);
    float p[NEXP], sum = 0.f;
    #pragma unroll
    for (int e = 0; e < NEXP; e++) { p[e] = expf(acc[e] - mx); sum += p[e]; }
    const float inv = 1.f / sum;
    #pragma unroll
    for (int e = 0; e < NEXP; e++) p[e] *= inv;
    #pragma unroll
    for (int e = 0; e < NEXP; e++) probs[(size_t)t * NEXP + e] = p[e];
    int i1 = 0;
    #pragma unroll
    for (int e = 1; e < NEXP; e++) if (p[e] > p[i1]) i1 = e;
    int i2 = (i1 == 0) ? 1 : 0;
    #pragma unroll
    for (int e = 0; e < NEXP; e++) if (e != i1 && p[e] > p[i2]) i2 = e;
    const float s2 = 1.f / (p[i1] + p[i2]);
    topIdx[2 * t] = i1; topIdx[2 * t + 1] = i2;
    topW[2 * t] = p[i1] * s2; topW[2 * t + 1] = p[i2] * s2;
  }
}

// ---------- per-expert stable compaction (one block per expert) ----------
__global__ __launch_bounds__(256) void k_build(const int* __restrict__ topIdx,
                                               const float* __restrict__ topW,
                                               int* __restrict__ listT,
                                               float* __restrict__ listW,
                                               int* __restrict__ listP,
                                               int* __restrict__ cnt) {
  const int e = blockIdx.x;
  const int tid = threadIdx.x, w = tid >> 6, lane = tid & 63;
  __shared__ int wt[4];
  int base = 0;
  for (int c = 0; c < NTOK / 256; ++c) {
    const int t = c * 256 + tid;
    const int i0 = topIdx[2 * t], i1 = topIdx[2 * t + 1];
    const int pr = (i0 == e) ? 1 : ((i1 == e) ? 2 : 0);
    const unsigned long long m = __ballot(pr != 0);
    const int wl = __popcll(m & ((1ull << lane) - 1ull));
    if (lane == 0) wt[w] = __popcll(m);
    __syncthreads();
    int wbase = 0;
    #pragma unroll
    for (int j = 0; j < 4; j++) if (j < w) wbase += wt[j];
    if (pr) {
      const int pos = base + wbase + wl;
      listT[e * NTOK + pos] = t;
      listW[e * NTOK + pos] = (pr == 1) ? topW[2 * t] : topW[2 * t + 1];
      listP[e * NTOK + pos] = pr;
    }
    base += wt[0] + wt[1] + wt[2] + wt[3];
    __syncthreads();
  }
  if (tid == 0) cnt[e] = base;
}

// ---------- tile map + slot arrays + inverse token->slot map ----------
__global__ __launch_bounds__(256) void k_tilemap(const int* __restrict__ cnt,
                                                 const int* __restrict__ listT,
                                                 const float* __restrict__ listW,
                                                 const int* __restrict__ listP,
                                                 int* __restrict__ tileExp,
                                                 int* __restrict__ tileM0,
                                                 int* __restrict__ slotTok,
                                                 float* __restrict__ slotW,
                                                 int* __restrict__ tokSlot) {
  __shared__ int offPad[NEXP + 1];
  __shared__ int cs[NEXP];
  const int tid = threadIdx.x;
  if (tid == 0) {
    int tt = 0, acc = 0;
    for (int e = 0; e < NEXP; e++) {
      cs[e] = cnt[e];
      offPad[e] = acc;
      const int tiles = (cs[e] + 127) >> 7;
      for (int i = 0; i < tiles; i++) { tileExp[tt] = e; tileM0[tt] = acc + i * 128; tt++; }
      acc += tiles * 128;
    }
    offPad[NEXP] = acc;
    for (int i = 0; i < NTOK / 128; i++) { tileExp[tt] = NEXP; tileM0[tt] = SHB + i * 128; tt++; }
    for (; tt < MAXT; tt++) tileExp[tt] = -1;
  }
  __syncthreads();
  for (int s = tid; s < CAPR; s += 256) {
    int tok = 0; float wv = 0.f; int pp = 0;
    #pragma unroll
    for (int e = 0; e < NEXP; e++)
      if (s >= offPad[e] && s < offPad[e + 1]) {
        const int i = s - offPad[e];
        if (i < cs[e]) {
          tok = listT[e * NTOK + i];
          wv = listW[e * NTOK + i];
          pp = listP[e * NTOK + i];
        }
      }
    slotTok[s] = tok; slotW[s] = wv;
    if (pp) tokSlot[2 * tok + (pp - 1)] = s;   // deterministic: unique (tok,pp)
  }
  for (int s = tid; s < NTOK; s += 256) { slotTok[SHB + s] = s; slotW[SHB + s] = 1.f; }
}

// ---------- gemm1: 1248 blocks (XCD-chunked), 128x128, 3-buf single-barrier,
//            coalesced staging + XOR-swizzled LDS ----------
__global__ __launch_bounds__(256, 2) void k_gemm1(const u16* __restrict__ xb,
                                                  const u16* __restrict__ w1t,
                                                  const u16* __restrict__ w2t,
                                                  const int* __restrict__ tileExp,
                                                  const int* __restrict__ tileM0,
                                                  const int* __restrict__ slotTok,
                                                  const float* __restrict__ slotW,
                                                  u16* __restrict__ hidden) {
  __shared__ alignas(16) u16 As[3][4096];
  __shared__ alignas(16) u16 B1s[3][4096];
  __shared__ alignas(16) u16 B2s[3][4096];
  const int chunk = (MAXT * (HID / 128)) >> 3;
  const int bid = blockIdx.x;
  const int wgid = (bid & 7) * chunk + (bid >> 3);
  const int bx = wgid % MAXT;
  const int by = wgid / MAXT;
  const int e = tileExp[bx];
  if (e < 0) return;
  const int m0 = tileM0[bx];
  const int nBase = by * 128;
  constexpr size_t SL = (size_t)HID * DIM;
  const u16* w1 = w1t + (size_t)e * SL;
  const u16* w2 = w2t + (size_t)e * SL;
  const int tid = threadIdx.x, w = tid >> 6, lane = tid & 63;
  const int wr = w >> 1, wc = w & 1;

  // ----- staging (coalesced): load j of wave w covers rows w*32+j*16+(lane>>2)
  const int qrow = lane >> 2;
  const int col0 = ((lane & 3) ^ ((lane >> 3) & 3)) * 8;   // swizzled k-col, u16
  const int tok0 = slotTok[m0 + w * 32 + qrow];
  const int tok1 = slotTok[m0 + w * 32 + 16 + qrow];
  const u16* gA0 = xb + (size_t)tok0 * DIM + col0;
  const u16* gA1 = xb + (size_t)tok1 * DIM + col0;
  const u16* gB1a = w1 + (size_t)(nBase + w * 32 + qrow) * DIM + col0;
  const u16* gB1b = w1 + (size_t)(nBase + w * 32 + 16 + qrow) * DIM + col0;
  const u16* gB2a = w2 + (size_t)(nBase + w * 32 + qrow) * DIM + col0;
  const u16* gB2b = w2 + (size_t)(nBase + w * 32 + 16 + qrow) * DIM + col0;
  const int l0 = (w * 2 + 0) * 512 + lane * 8;   // linear LDS dest, 16B/lane
  const int l1 = (w * 2 + 1) * 512 + lane * 8;

  f32x4 acc1[4][4], acc2[4][4];
  const f32x4 vz = {0.f, 0.f, 0.f, 0.f};
  #pragma unroll
  for (int m = 0; m < 4; m++)
    #pragma unroll
    for (int n = 0; n < 4; n++) { acc1[m][n] = vz; acc2[m][n] = vz; }

  // ----- ds_read frag offsets (swizzled, XOR folds to per-thread const)
  const int rbase = lane & 15;
  const int swz = (lane >> 4) ^ ((rbase >> 1) & 3);
  const int aoffB = (wr * 64 + rbase) * 32 + swz * 8;
  const int boffB = (wc * 64 + rbase) * 32 + swz * 8;

#define G1_STAGE(buf, kk) do {                                                \
    GLDS16(gA0  + (kk), &As[buf][l0]);  GLDS16(gA1  + (kk), &As[buf][l1]);    \
    GLDS16(gB1a + (kk), &B1s[buf][l0]); GLDS16(gB1b + (kk), &B1s[buf][l1]);   \
    GLDS16(gB2a + (kk), &B2s[buf][l0]); GLDS16(gB2b + (kk), &B2s[buf][l1]);   \
  } while (0)

#define G1_BODY(buf, vm, dostage, kk) do {                                    \
    SCHED(); VMCNT(vm); SBAR(); SCHED();                                      \
    if (dostage) { G1_STAGE((buf + 2) % 3, kk); SCHED(); }                    \
    bf16x8 av[4], b1v[4], b2v[4];                                             \
    _Pragma("unroll")                                                         \
    for (int m = 0; m < 4; m++) av[m] = *(const bf16x8*)&As[buf][aoffB + m * 512]; \
    _Pragma("unroll")                                                         \
    for (int n = 0; n < 4; n++) {                                             \
      b1v[n] = *(const bf16x8*)&B1s[buf][boffB + n * 512];                    \
      b2v[n] = *(const bf16x8*)&B2s[buf][boffB + n * 512];                    \
    }                                                                         \
    __builtin_amdgcn_s_setprio(1);                                            \
    _Pragma("unroll")                                                         \
    for (int m = 0; m < 4; m++)                                               \
      _Pragma("unroll")                                                       \
      for (int n = 0; n < 4; n++) {                                           \
        acc1[m][n] = __builtin_amdgcn_mfma_f32_16x16x32_bf16(av[m], b1v[n], acc1[m][n], 0, 0, 0); \
        acc2[m][n] = __builtin_amdgcn_mfma_f32_16x16x32_bf16(av[m], b2v[n], acc2[m][n], 0, 0, 0); \
      }                                                                       \
    __builtin_amdgcn_s_setprio(0);                                            \
  } while (0)

  // 24 bodies; stage-ahead-2; 6 loads/stage -> steady VMCNT(6)
  G1_STAGE(0, 0);  SCHED();
  G1_STAGE(1, 32); SCHED();
  for (int t = 0; t < 21; t += 3) {
    G1_BODY(0, 6, true, (t + 2) * 32);
    G1_BODY(1, 6, true, (t + 3) * 32);
    G1_BODY(2, 6, true, (t + 4) * 32);
  }
  G1_BODY(0, 6, true, 23 * 32);
  G1_BODY(1, 6, false, 0);
  G1_BODY(2, 0, false, 0);
#undef G1_BODY
#undef G1_STAGE

  #pragma unroll
  for (int m = 0; m < 4; m++)
    #pragma unroll
    for (int r = 0; r < 4; r++) {
      const int slot = m0 + wr * 64 + m * 16 + (lane >> 4) * 4 + r;
      const float cwv = slotW[slot];
      #pragma unroll
      for (int n = 0; n < 4; n++) {
        const int hcol = nBase + wc * 64 + n * 16 + (lane & 15);
        const float v1 = acc1[m][n][r], v2 = acc2[m][n][r];
        hidden[(size_t)slot * HID + hcol] = f2bf((v1 / (1.f + __expf(-v1))) * v2 * cwv);
      }
    }
}

// ---------- gemm2: 624 blocks (all-resident @3/CU), 3-buf single-barrier,
//            coalesced staging + XOR-swizzled LDS ----------
__global__ __launch_bounds__(256, 3) void k_gemm2(const u16* __restrict__ hid,
                                                  const u16* __restrict__ pjt,
                                                  const int* __restrict__ tileExp,
                                                  const int* __restrict__ tileM0,
                                                  float* __restrict__ g2) {
  __shared__ alignas(16) u16 As[3][4096];
  __shared__ alignas(16) u16 Bs[3][4096];
  const int chunk = (MAXT * (DIM / 128)) >> 3;   // 624/8 = 78
  const int bid = blockIdx.x;
  const int wgid = (bid & 7) * chunk + (bid >> 3);
  const int bx = wgid % MAXT;
  const int by = wgid / MAXT;
  const int e = tileExp[bx];
  if (e < 0) return;
  const int m0 = tileM0[bx];
  const int nBase = by * 128;
  constexpr size_t SL = (size_t)HID * DIM;
  const u16* pj = pjt + (size_t)e * SL;
  const int tid = threadIdx.x, w = tid >> 6, lane = tid & 63;
  const int wr = w >> 1, wc = w & 1;

  const int qrow = lane >> 2;
  const int col0 = ((lane & 3) ^ ((lane >> 3) & 3)) * 8;
  const u16* gA0 = hid + (size_t)(m0 + w * 32 + qrow) * HID + col0;
  const u16* gA1 = hid + (size_t)(m0 + w * 32 + 16 + qrow) * HID + col0;
  const u16* gBa = pj + (size_t)(nBase + w * 32 + qrow) * HID + col0;
  const u16* gBb = pj + (size_t)(nBase + w * 32 + 16 + qrow) * HID + col0;
  const int l0 = (w * 2 + 0) * 512 + lane * 8;
  const int l1 = (w * 2 + 1) * 512 + lane * 8;

  f32x4 acc[4][4];
  const f32x4 vz = {0.f, 0.f, 0.f, 0.f};
  #pragma unroll
  for (int m = 0; m < 4; m++)
    #pragma unroll
    for (int n = 0; n < 4; n++) acc[m][n] = vz;

  const int rbase = lane & 15;
  const int swz = (lane >> 4) ^ ((rbase >> 1) & 3);
  const int aoffB = (wr * 64 + rbase) * 32 + swz * 8;
  const int boffB = (wc * 64 + rbase) * 32 + swz * 8;

#define G2_STAGE(buf, kk) do {                                                \
    GLDS16(gA0 + (kk), &As[buf][l0]); GLDS16(gA1 + (kk), &As[buf][l1]);       \
    GLDS16(gBa + (kk), &Bs[buf][l0]); GLDS16(gBb + (kk), &Bs[buf][l1]);       \
  } while (0)

#define G2_BODY(buf, vm, dostage, kk) do {                                    \
    SCHED(); VMCNT(vm); SBAR(); SCHED();                                      \
    if (dostage) { G2_STAGE((buf + 2) % 3, kk); SCHED(); }                    \
    bf16x8 av[4], bv[4];                                                      \
    _Pragma("unroll")                                                         \
    for (int m = 0; m < 4; m++) av[m] = *(const bf16x8*)&As[buf][aoffB + m * 512]; \
    _Pragma("unroll")                                                         \
    for (int n = 0; n < 4; n++) bv[n] = *(const bf16x8*)&Bs[buf][boffB + n * 512]; \
    __builtin_amdgcn_s_setprio(1);                                            \
    _Pragma("unroll")                                                         \
    for (int m = 0; m < 4; m++)                                               \
      _Pragma("unroll")                                                       \
      for (int n = 0; n < 4; n++)                                             \
        acc[m][n] = __builtin_amdgcn_mfma_f32_16x16x32_bf16(av[m], bv[n], acc[m][n], 0, 0, 0); \
    __builtin_amdgcn_s_setprio(0);                                            \
  } while (0)

  // 48 bodies; stage-ahead-2; 4 loads/stage -> steady VMCNT(4)
  G2_STAGE(0, 0);  SCHED();
  G2_STAGE(1, 32); SCHED();
  for (int t = 0; t < 45; t += 3) {
    G2_BODY(0, 4, true, (t + 2) * 32);
    G2_BODY(1, 4, true, (t + 3) * 32);
    G2_BODY(2, 4, true, (t + 4) * 32);
  }
  G2_BODY(0, 4, true, 47 * 32);
  G2_BODY(1, 4, false, 0);
  G2_BODY(2, 0, false, 0);
#undef G2_BODY
#undef G2_STAGE

  #pragma unroll
  for (int m = 0; m < 4; m++)
    #pragma unroll
    for (int r = 0; r < 4; r++) {
      const int slot = m0 + wr * 64 + m * 16 + (lane >> 4) * 4 + r;
      #pragma unroll
      for (int n = 0; n < 4; n++) {
        const int dcol = nBase + wc * 64 + n * 16 + (lane & 15);
        g2[(size_t)slot * DIM + dcol] = acc[m][n][r];
      }
    }
}

// ---------- combine: out[t] = g2[minSlot] + g2[maxSlot] + g2[shared]  (deterministic) ----------
__global__ __launch_bounds__(192) void k_combine(const float* __restrict__ g2,
                                                 const int* __restrict__ tokSlot,
                                                 float* __restrict__ out) {
  const int t = blockIdx.x, d4 = threadIdx.x;
  const int sA = tokSlot[2 * t], sB = tokSlot[2 * t + 1];
  const int lo = sA < sB ? sA : sB;
  const int hi = sA < sB ? sB : sA;
  const float4 a = ((const float4*)(g2 + (size_t)lo * DIM))[d4];
  const float4 b = ((const float4*)(g2 + (size_t)hi * DIM))[d4];
  const float4 c = ((const float4*)(g2 + (size_t)(SHB + t) * DIM))[d4];
  float4 o;
  o.x = a.x + b.x + c.x; o.y = a.y + b.y + c.y;
  o.z = a.z + b.z + c.z; o.w = a.w + b.w + c.w;
  ((float4*)(out + (size_t)t * DIM))[d4] = o;
}

// ---------- launch ----------
extern "C" void kernel_launch(void* const* d_in, const int* in_sizes, int n_in,
                              void* d_out, int out_size, void* d_ws, size_t ws_size,
                              hipStream_t stream) {
  const float* x     = (const float*)d_in[0];
  const float* rw    = (const float*)d_in[1];
  const float* sw1   = (const float*)d_in[2];
  const float* sw2   = (const float*)d_in[3];
  const float* sproj = (const float*)d_in[4];
  const float* ew1   = (const float*)d_in[5];
  const float* ew2   = (const float*)d_in[6];
  const float* eproj = (const float*)d_in[7];
  float* out   = (float*)d_out;
  float* probs = out + (size_t)NTOK * DIM;

  constexpr size_t SL = (size_t)HID * DIM;
  constexpr size_t off_xb   = 0;
  constexpr size_t off_w1t  = 6291456;
  constexpr size_t off_w2t  = off_w1t + 2 * 9 * SL;
  constexpr size_t off_pjt  = off_w2t + 2 * 9 * SL;
  constexpr size_t off_hid  = off_pjt + 2 * 9 * SL;              // 69,992,448
  constexpr size_t off_g2   = off_hid + (size_t)NSLOT * HID * 2; // 110,886,912
  constexpr size_t off_meta = off_g2 + (size_t)NSLOT * DIM * 4;  // 151,781,376

  char* ws = (char*)d_ws;
  u16*   xb   = (u16*)(ws + off_xb);
  u16*   w1t  = (u16*)(ws + off_w1t);
  u16*   w2t  = (u16*)(ws + off_w2t);
  u16*   pjt  = (u16*)(ws + off_pjt);
  u16*   hid  = (u16*)(ws + off_hid);
  float* g2   = (float*)(ws + off_g2);
  char*  meta = ws + off_meta;
  int*   topIdx  = (int*)meta;                        // 32 KB
  float* topW    = (float*)(meta + 32768);            // 32 KB
  int*   listT   = (int*)(meta + 65536);              // 128 KB
  float* listW   = (float*)(meta + 196608);           // 128 KB
  int*   listP   = (int*)(meta + 327680);             // 128 KB
  int*   cnt     = (int*)(meta + 458752);
  int*   tileExp = (int*)(meta + 459264);
  int*   tileM0  = (int*)(meta + 459776);
  int*   slotTok = (int*)(meta + 460288);             // 52 KB
  float* slotW   = (float*)(meta + 513536);           // 52 KB
  int*   tokSlot = (int*)(meta + 566784);             // 32 KB

  k_router<<<NTOK, 64, 0, stream>>>(x, rw, probs, topIdx, topW, xb);
  k_tr_all<<<dim3(HID / 64, DIM / 64, 27), dim3(64, 4), 0, stream>>>(
      ew1, sw1, ew2, sw2, eproj, sproj, w1t);

  k_build<<<NEXP, 256, 0, stream>>>(topIdx, topW, listT, listW, listP, cnt);
  k_tilemap<<<1, 256, 0, stream>>>(cnt, listT, listW, listP, tileExp, tileM0,
                                   slotTok, slotW, tokSlot);

  k_gemm1<<<MAXT * (HID / 128), 256, 0, stream>>>(xb, w1t, w2t, tileExp, tileM0,
                                                  slotTok, slotW, hid);
  k_gemm2<<<MAXT * (DIM / 128), 256, 0, stream>>>(hid, pjt, tileExp, tileM0, g2);
  k_combine<<<NTOK, 192, 0, stream>>>(g2, tokSlot, out);
}

// Round 8
// 215.309 us; speedup vs baseline: 1.4458x; 1.0403x over previous
//
#include <hip/hip_runtime.h>

typedef unsigned short u16;
typedef __bf16 bf16x8 __attribute__((ext_vector_type(8)));
typedef float f32x4 __attribute__((ext_vector_type(4)));

// ---------- helpers ----------
__device__ __forceinline__ u16 f2bf(float f) {
  union { float f; unsigned u; } v; v.f = f;
  return (u16)((v.u + 0x7fffu + ((v.u >> 16) & 1u)) >> 16);   // RNE
}

#define GLDS16(g, l)                                                          \
  __builtin_amdgcn_global_load_lds(                                           \
      (const __attribute__((address_space(1))) void*)(g),                     \
      (__attribute__((address_space(3))) void*)(l), 16, 0, 0)

#define SBAR()  __builtin_amdgcn_s_barrier()
#define SCHED() __builtin_amdgcn_sched_barrier(0)
#define VMCNT(n) asm volatile("s_waitcnt vmcnt(" #n ")" ::: "memory")

// ---------- sizes ----------
#define NTOK 4096     // B*T
#define DIM  768
#define HID  1536
#define NEXP 8
#define CAPR 10240    // routed slot capacity (8192 + per-expert pad to 256)
#define SHB  10240    // shared-expert slot base
#define NSLOT 14336   // CAPR + NTOK
#define MAXT1 56      // 256-row M-tiles: <=40 routed + 16 shared
#define MAXT2 112     // 128-row M-tiles (2 per 256-tile)

// ---------- fused transpose: 27 slices f32[R][C] -> bf16[C][R], 64x64 tiles ----------
__global__ __launch_bounds__(256) void k_tr_all(const float* __restrict__ ew1,
                                                const float* __restrict__ sw1,
                                                const float* __restrict__ ew2,
                                                const float* __restrict__ sw2,
                                                const float* __restrict__ eproj,
                                                const float* __restrict__ sproj,
                                                u16* __restrict__ dstBase) {
  __shared__ u16 tile[64][65];
  constexpr size_t SL = (size_t)HID * DIM;
  const int z = blockIdx.z;
  const float* src;
  int R, C, bxx = blockIdx.x, byy = blockIdx.y;
  if (z < 9)       { src = (z < 8) ? ew1 + (size_t)z * SL : sw1; R = DIM; C = HID; }
  else if (z < 18) { const int q = z - 9;  src = (q < 8) ? ew2 + (size_t)q * SL : sw2; R = DIM; C = HID; }
  else             { const int q = z - 18; src = (q < 8) ? eproj + (size_t)q * SL : sproj;
                     R = HID; C = DIM; const int t = bxx; bxx = byy; byy = t; }
  u16* dst = dstBase + (size_t)z * SL;
  const int c0 = bxx * 64, r0 = byy * 64;
  const int tx = threadIdx.x, ty = threadIdx.y;   // (64,4)
  #pragma unroll
  for (int i = 0; i < 16; i++)
    tile[ty + 4 * i][tx] = f2bf(src[(size_t)(r0 + ty + 4 * i) * C + c0 + tx]);
  __syncthreads();
  #pragma unroll
  for (int i = 0; i < 16; i++)
    dst[(size_t)(c0 + ty + 4 * i) * R + r0 + tx] = tile[tx][ty + 4 * i];
}

// ---------- router: probs + top-2 (renormalized) + x->bf16 ----------
__global__ __launch_bounds__(64) void k_router(const float* __restrict__ x,
                                               const float* __restrict__ rw,
                                               float* __restrict__ probs,
                                               int* __restrict__ topIdx,
                                               float* __restrict__ topW,
                                               u16* __restrict__ xb) {
  const int t = blockIdx.x;
  const int lane = threadIdx.x;
  const float* xr = x + (size_t)t * DIM;
  u16* xbr = xb + (size_t)t * DIM;
  float acc[NEXP] = {0, 0, 0, 0, 0, 0, 0, 0};
  #pragma unroll
  for (int i = 0; i < DIM / 64; i++) {
    const int d = lane + 64 * i;
    const float xv = xr[d];
    xbr[d] = f2bf(xv);
    #pragma unroll
    for (int e = 0; e < NEXP; e++) acc[e] += xv * rw[e * DIM + d];
  }
  #pragma unroll
  for (int e = 0; e < NEXP; e++)
    #pragma unroll
    for (int s = 32; s > 0; s >>= 1) acc[e] += __shfl_xor(acc[e], s, 64);
  if (lane == 0) {
    float mx = acc[0];
    #pragma unroll
    for (int e = 1; e < NEXP; e++) mx = fmaxf(mx, acc[e]);
    float p[NEXP], sum = 0.f;
    #pragma unroll
    for (int e = 0; e < NEXP; e++) { p[e] = expf(acc[e] - mx); sum += p[e]; }
    const float inv = 1.f / sum;
    #pragma unroll
    for (int e = 0; e < NEXP; e++) p[e] *= inv;
    #pragma unroll
    for (int e = 0; e < NEXP; e++) probs[(size_t)t * NEXP + e] = p[e];
    int i1 = 0;
    #pragma unroll
    for (int e = 1; e < NEXP; e++) if (p[e] > p[i1]) i1 = e;
    int i2 = (i1 == 0) ? 1 : 0;
    #pragma unroll
    for (int e = 0; e < NEXP; e++) if (e != i1 && p[e] > p[i2]) i2 = e;
    const float s2 = 1.f / (p[i1] + p[i2]);
    topIdx[2 * t] = i1; topIdx[2 * t + 1] = i2;
    topW[2 * t] = p[i1] * s2; topW[2 * t + 1] = p[i2] * s2;
  }
}

// ---------- per-expert stable compaction (one block per expert) ----------
__global__ __launch_bounds__(256) void k_build(const int* __restrict__ topIdx,
                                               const float* __restrict__ topW,
                                               int* __restrict__ listT,
                                               float* __restrict__ listW,
                                               int* __restrict__ listP,
                                               int* __restrict__ cnt) {
  const int e = blockIdx.x;
  const int tid = threadIdx.x, w = tid >> 6, lane = tid & 63;
  __shared__ int wt[4];
  int base = 0;
  for (int c = 0; c < NTOK / 256; ++c) {
    const int t = c * 256 + tid;
    const int i0 = topIdx[2 * t], i1 = topIdx[2 * t + 1];
    const int pr = (i0 == e) ? 1 : ((i1 == e) ? 2 : 0);
    const unsigned long long m = __ballot(pr != 0);
    const int wl = __popcll(m & ((1ull << lane) - 1ull));
    if (lane == 0) wt[w] = __popcll(m);
    __syncthreads();
    int wbase = 0;
    #pragma unroll
    for (int j = 0; j < 4; j++) if (j < w) wbase += wt[j];
    if (pr) {
      const int pos = base + wbase + wl;
      listT[e * NTOK + pos] = t;
      listW[e * NTOK + pos] = (pr == 1) ? topW[2 * t] : topW[2 * t + 1];
      listP[e * NTOK + pos] = pr;
    }
    base += wt[0] + wt[1] + wt[2] + wt[3];
    __syncthreads();
  }
  if (tid == 0) cnt[e] = base;
}

// ---------- tile maps (256 for gemm1, 128 for gemm2) + slot arrays ----------
__global__ __launch_bounds__(256) void k_tilemap(const int* __restrict__ cnt,
                                                 const int* __restrict__ listT,
                                                 const float* __restrict__ listW,
                                                 const int* __restrict__ listP,
                                                 int* __restrict__ tE1, int* __restrict__ tM1,
                                                 int* __restrict__ tE2, int* __restrict__ tM2,
                                                 int* __restrict__ slotTok,
                                                 float* __restrict__ slotW,
                                                 int* __restrict__ tokSlot) {
  __shared__ int offPad[NEXP + 1];
  __shared__ int cs[NEXP];
  const int tid = threadIdx.x;
  if (tid == 0) {
    int tt = 0, acc = 0;
    for (int e = 0; e < NEXP; e++) {
      cs[e] = cnt[e];
      offPad[e] = acc;
      const int tiles = (cs[e] + 255) >> 8;
      for (int i = 0; i < tiles; i++) { tE1[tt] = e; tM1[tt] = acc + i * 256; tt++; }
      acc += tiles * 256;
    }
    offPad[NEXP] = acc;
    for (int i = 0; i < NTOK / 256; i++) { tE1[tt] = NEXP; tM1[tt] = SHB + i * 256; tt++; }
    for (; tt < MAXT1; tt++) { tE1[tt] = -1; tM1[tt] = 0; }
    for (int j = 0; j < MAXT1; j++) {
      tE2[2 * j] = tE1[j];     tM2[2 * j] = tM1[j];
      tE2[2 * j + 1] = tE1[j]; tM2[2 * j + 1] = tM1[j] + 128;
    }
  }
  __syncthreads();
  for (int s = tid; s < CAPR; s += 256) {
    int tok = 0; float wv = 0.f; int pp = 0;
    #pragma unroll
    for (int e = 0; e < NEXP; e++)
      if (s >= offPad[e] && s < offPad[e + 1]) {
        const int i = s - offPad[e];
        if (i < cs[e]) {
          tok = listT[e * NTOK + i];
          wv = listW[e * NTOK + i];
          pp = listP[e * NTOK + i];
        }
      }
    slotTok[s] = tok; slotW[s] = wv;
    if (pp) tokSlot[2 * tok + (pp - 1)] = s;
  }
  for (int s = tid; s < NTOK; s += 256) { slotTok[SHB + s] = s; slotW[SHB + s] = 1.f; }
}

// ---------- gemm1: 8-phase 256x128xBK64, 8 waves (4Mx2N), dual-B, 2-dbuf JIT staging ----
// LDS per dbuf (u16): A[0..16383] (2 k-halves x 256rows x 4 chunks), B1[16384..24575],
// B2[24576..32767]. chunk(row,kslot) = row*4 + (kslot ^ ((row>>1)&3)) within k-half.
// Units/K-tile: u0=A-kh0(2 glds) u1=B12-kh0(2) u2=A-kh1(2) u3=B12-kh1(2).
// Phase p stages unit (p-2)&3 of tile ((p-2)>>2)+2; vmcnt(8) at every odd phase.
__global__ __launch_bounds__(512, 2) void k_gemm1(const u16* __restrict__ xb,
                                                  const u16* __restrict__ w1t,
                                                  const u16* __restrict__ w2t,
                                                  const int* __restrict__ tE1,
                                                  const int* __restrict__ tM1,
                                                  const int* __restrict__ slotTok,
                                                  const float* __restrict__ slotW,
                                                  u16* __restrict__ hidden) {
  __shared__ alignas(16) u16 L[2][32768];
  const int bid = blockIdx.x;                       // 672 = 8*84
  const int wgid = (bid & 7) * 84 + (bid >> 3);
  const int bx = wgid % MAXT1, by = wgid / MAXT1;
  const int e = tE1[bx];
  if (e < 0) return;
  const int m0 = tM1[bx];
  const int nBase = by * 128;
  constexpr size_t SL = (size_t)HID * DIM;
  const u16* w1 = w1t + (size_t)e * SL;
  const u16* w2 = w2t + (size_t)e * SL;
  const int tid = threadIdx.x, w = tid >> 6, lane = tid & 63;
  const int wr = w >> 1, wc = w & 1;

  // staging: 512 thr/line; row = tid>>2, swizzled 16B col within k-half
  const int srow = tid >> 2;
  const int kcol = ((tid & 3) ^ ((tid >> 3) & 3)) * 8;
  const int tokA0 = slotTok[m0 + srow];
  const int tokA1 = slotTok[m0 + 128 + srow];
  const u16* gA0 = xb + (size_t)tokA0 * DIM + kcol;
  const u16* gA1 = xb + (size_t)tokA1 * DIM + kcol;
  const u16* gB1 = w1 + (size_t)(nBase + srow) * DIM + kcol;
  const u16* gB2 = w2 + (size_t)(nBase + srow) * DIM + kcol;
  const int dA0 = tid * 8, dA1 = 4096 + tid * 8, dB = tid * 8;

  // read-side frag offsets (u16)
  const int rl = lane & 15;
  const int kq = lane >> 4;
  const int aBase = (wr * 64 + rl) * 32 + (kq ^ ((rl >> 1) & 3)) * 8;
  const int bBase = (wc * 64 + rl) * 32 + (kq ^ ((rl >> 1) & 3)) * 8;

  f32x4 acc1[4][4], acc2[4][4];
  const f32x4 vz = {0.f, 0.f, 0.f, 0.f};
  #pragma unroll
  for (int m = 0; m < 4; m++)
    #pragma unroll
    for (int n = 0; n < 4; n++) { acc1[m][n] = vz; acc2[m][n] = vz; }

#define G1_STA(d, koff, kh) do {                                              \
    GLDS16(gA0 + (koff), &L[d][(kh) * 8192 + dA0]);                           \
    GLDS16(gA1 + (koff), &L[d][(kh) * 8192 + dA1]); } while (0)
#define G1_STB(d, koff, kh) do {                                              \
    GLDS16(gB1 + (koff), &L[d][16384 + (kh) * 4096 + dB]);                    \
    GLDS16(gB2 + (koff), &L[d][24576 + (kh) * 4096 + dB]); } while (0)
#define G1_RDB(d, kh) do { _Pragma("unroll")                                  \
    for (int n = 0; n < 4; n++) {                                             \
      b1v[n] = *(const bf16x8*)&L[d][16384 + (kh) * 4096 + bBase + n * 512];  \
      b2v[n] = *(const bf16x8*)&L[d][24576 + (kh) * 4096 + bBase + n * 512]; } } while (0)
#define G1_RDA(d, kh, mp) do { _Pragma("unroll")                              \
    for (int j = 0; j < 2; j++)                                               \
      av[j] = *(const bf16x8*)&L[d][(kh) * 8192 + aBase + ((mp) * 2 + j) * 512]; } while (0)
#define G1_MM(mp) do { __builtin_amdgcn_s_setprio(1);                         \
    _Pragma("unroll") for (int j = 0; j < 2; j++)                             \
      _Pragma("unroll") for (int n = 0; n < 4; n++) {                         \
        acc1[(mp) * 2 + j][n] = __builtin_amdgcn_mfma_f32_16x16x32_bf16(av[j], b1v[n], acc1[(mp) * 2 + j][n], 0, 0, 0); \
        acc2[(mp) * 2 + j][n] = __builtin_amdgcn_mfma_f32_16x16x32_bf16(av[j], b2v[n], acc2[(mp) * 2 + j][n], 0, 0, 0); } \
    __builtin_amdgcn_s_setprio(0); } while (0)

  // prologue: tiles 0 (all 4 units) + 1 (kh0 units) = 6 units / 12 lines
  G1_STA(0, 0, 0);  G1_STB(0, 0, 0);
  G1_STA(0, 32, 1); G1_STB(0, 32, 1);
  G1_STA(1, 64, 0); G1_STB(1, 64, 0);
  SCHED(); VMCNT(8); SBAR(); SCHED();

  bf16x8 av[2], b1v[4], b2v[4];
  for (int i = 0; i < 5; i++) {
    const int kOff = i * 128;
    // q0: tile 2i kh0 mp0 | stage A-kh1 of t(2i+1)
    G1_RDB(0, 0); G1_RDA(0, 0, 0); SCHED(); G1_STA(1, kOff + 96, 1); SCHED();
    G1_MM(0); SCHED(); SBAR(); SCHED();
    // q1: mp1 | stage B-kh1 t(2i+1)
    G1_RDA(0, 0, 1); SCHED(); G1_STB(1, kOff + 96, 1); SCHED();
    G1_MM(1); SCHED(); VMCNT(8); SBAR(); SCHED();
    // q2: tile 2i kh1 mp0 | stage A-kh0 t(2i+2)
    G1_RDB(0, 1); G1_RDA(0, 1, 0); SCHED(); G1_STA(0, kOff + 128, 0); SCHED();
    G1_MM(0); SCHED(); SBAR(); SCHED();
    // q3
    G1_RDA(0, 1, 1); SCHED(); G1_STB(0, kOff + 128, 0); SCHED();
    G1_MM(1); SCHED(); VMCNT(8); SBAR(); SCHED();
    // q4: tile 2i+1 kh0 mp0 | stage A-kh1 t(2i+2)
    G1_RDB(1, 0); G1_RDA(1, 0, 0); SCHED(); G1_STA(0, kOff + 160, 1); SCHED();
    G1_MM(0); SCHED(); SBAR(); SCHED();
    // q5
    G1_RDA(1, 0, 1); SCHED(); G1_STB(0, kOff + 160, 1); SCHED();
    G1_MM(1); SCHED(); VMCNT(8); SBAR(); SCHED();
    // q6: tile 2i+1 kh1 mp0 | stage A-kh0 t(2i+3)
    G1_RDB(1, 1); G1_RDA(1, 1, 0); SCHED(); G1_STA(1, kOff + 192, 0); SCHED();
    G1_MM(0); SCHED(); SBAR(); SCHED();
    // q7
    G1_RDA(1, 1, 1); SCHED(); G1_STB(1, kOff + 192, 0); SCHED();
    G1_MM(1); SCHED(); VMCNT(8); SBAR(); SCHED();
  }
  // tail: tiles 10 (d0), 11 (d1); last stages = t11 kh1; vmcnt 8/4/0
  G1_RDB(0, 0); G1_RDA(0, 0, 0); SCHED(); G1_STA(1, 736, 1); SCHED();
  G1_MM(0); SCHED(); SBAR(); SCHED();
  G1_RDA(0, 0, 1); SCHED(); G1_STB(1, 736, 1); SCHED();
  G1_MM(1); SCHED(); VMCNT(8); SBAR(); SCHED();
  G1_RDB(0, 1); G1_RDA(0, 1, 0); SCHED(); G1_MM(0); SCHED(); SBAR(); SCHED();
  G1_RDA(0, 1, 1); SCHED(); G1_MM(1); SCHED(); VMCNT(4); SBAR(); SCHED();
  G1_RDB(1, 0); G1_RDA(1, 0, 0); SCHED(); G1_MM(0); SCHED(); SBAR(); SCHED();
  G1_RDA(1, 0, 1); SCHED(); G1_MM(1); SCHED(); VMCNT(0); SBAR(); SCHED();
  G1_RDB(1, 1); G1_RDA(1, 1, 0); SCHED(); G1_MM(0); SCHED(); SBAR(); SCHED();
  G1_RDA(1, 1, 1); SCHED(); G1_MM(1);
#undef G1_STA
#undef G1_STB
#undef G1_RDB
#undef G1_RDA
#undef G1_MM

  #pragma unroll
  for (int m = 0; m < 4; m++)
    #pragma unroll
    for (int r = 0; r < 4; r++) {
      const int slot = m0 + wr * 64 + m * 16 + (lane >> 4) * 4 + r;
      const float cwv = slotW[slot];
      #pragma unroll
      for (int n = 0; n < 4; n++) {
        const int hcol = nBase + wc * 64 + n * 16 + (lane & 15);
        const float v1 = acc1[m][n][r], v2 = acc2[m][n][r];
        hidden[(size_t)slot * HID + hcol] = f2bf((v1 / (1.f + __expf(-v1))) * v2 * cwv);
      }
    }
}

// ---------- gemm2: 672 blocks, 128x128, 3-buf single-barrier (proven r5-r7) ----------
__global__ __launch_bounds__(256, 3) void k_gemm2(const u16* __restrict__ hid,
                                                  const u16* __restrict__ pjt,
                                                  const int* __restrict__ tE2,
                                                  const int* __restrict__ tM2,
                                                  float* __restrict__ g2) {
  __shared__ alignas(16) u16 As[3][4096];
  __shared__ alignas(16) u16 Bs[3][4096];
  const int bid = blockIdx.x;                      // 672 = 8*84
  const int wgid = (bid & 7) * 84 + (bid >> 3);
  const int bx = wgid % MAXT2;
  const int by = wgid / MAXT2;
  const int e = tE2[bx];
  if (e < 0) return;
  const int m0 = tM2[bx];
  const int nBase = by * 128;
  constexpr size_t SL = (size_t)HID * DIM;
  const u16* pj = pjt + (size_t)e * SL;
  const int tid = threadIdx.x, w = tid >> 6, lane = tid & 63;
  const int wr = w >> 1, wc = w & 1;

  const int qrow = lane >> 2;
  const int col0 = ((lane & 3) ^ ((lane >> 3) & 3)) * 8;
  const u16* gA0 = hid + (size_t)(m0 + w * 32 + qrow) * HID + col0;
  const u16* gA1 = hid + (size_t)(m0 + w * 32 + 16 + qrow) * HID + col0;
  const u16* gBa = pj + (size_t)(nBase + w * 32 + qrow) * HID + col0;
  const u16* gBb = pj + (size_t)(nBase + w * 32 + 16 + qrow) * HID + col0;
  const int l0 = (w * 128 + lane) * 8, l1 = (w * 128 + lane + 64) * 8;

  f32x4 acc[4][4];
  const f32x4 vz = {0.f, 0.f, 0.f, 0.f};
  #pragma unroll
  for (int m = 0; m < 4; m++)
    #pragma unroll
    for (int n = 0; n < 4; n++) acc[m][n] = vz;

  const int rbase = lane & 15;
  const int swz = (lane >> 4) ^ ((rbase >> 1) & 3);
  const int aoffB = (wr * 64 + rbase) * 32 + swz * 8;
  const int boffB = (wc * 64 + rbase) * 32 + swz * 8;

#define G2_STAGE(buf, kk) do {                                                \
    GLDS16(gA0 + (kk), &As[buf][l0]); GLDS16(gA1 + (kk), &As[buf][l1]);       \
    GLDS16(gBa + (kk), &Bs[buf][l0]); GLDS16(gBb + (kk), &Bs[buf][l1]);       \
  } while (0)

#define G2_BODY(buf, vm, dostage, kk) do {                                    \
    SCHED(); VMCNT(vm); SBAR(); SCHED();                                      \
    if (dostage) { G2_STAGE((buf + 2) % 3, kk); SCHED(); }                    \
    bf16x8 av[4], bv[4];                                                      \
    _Pragma("unroll")                                                         \
    for (int m = 0; m < 4; m++) av[m] = *(const bf16x8*)&As[buf][aoffB + m * 512]; \
    _Pragma("unroll")                                                         \
    for (int n = 0; n < 4; n++) bv[n] = *(const bf16x8*)&Bs[buf][boffB + n * 512]; \
    __builtin_amdgcn_s_setprio(1);                                            \
    _Pragma("unroll")                                                         \
    for (int m = 0; m < 4; m++)                                               \
      _Pragma("unroll")                                                       \
      for (int n = 0; n < 4; n++)                                             \
        acc[m][n] = __builtin_amdgcn_mfma_f32_16x16x32_bf16(av[m], bv[n], acc[m][n], 0, 0, 0); \
    __builtin_amdgcn_s_setprio(0);                                            \
  } while (0)

  G2_STAGE(0, 0);  SCHED();
  G2_STAGE(1, 32); SCHED();
  for (int t = 0; t < 45; t += 3) {
    G2_BODY(0, 4, true, (t + 2) * 32);
    G2_BODY(1, 4, true, (t + 3) * 32);
    G2_BODY(2, 4, true, (t + 4) * 32);
  }
  G2_BODY(0, 4, true, 47 * 32);
  G2_BODY(1, 4, false, 0);
  G2_BODY(2, 0, false, 0);
#undef G2_BODY
#undef G2_STAGE

  #pragma unroll
  for (int m = 0; m < 4; m++)
    #pragma unroll
    for (int r = 0; r < 4; r++) {
      const int slot = m0 + wr * 64 + m * 16 + (lane >> 4) * 4 + r;
      #pragma unroll
      for (int n = 0; n < 4; n++) {
        const int dcol = nBase + wc * 64 + n * 16 + (lane & 15);
        g2[(size_t)slot * DIM + dcol] = acc[m][n][r];
      }
    }
}

// ---------- combine ----------
__global__ __launch_bounds__(192) void k_combine(const float* __restrict__ g2,
                                                 const int* __restrict__ tokSlot,
                                                 float* __restrict__ out) {
  const int t = blockIdx.x, d4 = threadIdx.x;
  const int sA = tokSlot[2 * t], sB = tokSlot[2 * t + 1];
  const int lo = sA < sB ? sA : sB;
  const int hi = sA < sB ? sB : sA;
  const float4 a = ((const float4*)(g2 + (size_t)lo * DIM))[d4];
  const float4 b = ((const float4*)(g2 + (size_t)hi * DIM))[d4];
  const float4 c = ((const float4*)(g2 + (size_t)(SHB + t) * DIM))[d4];
  float4 o;
  o.x = a.x + b.x + c.x; o.y = a.y + b.y + c.y;
  o.z = a.z + b.z + c.z; o.w = a.w + b.w + c.w;
  ((float4*)(out + (size_t)t * DIM))[d4] = o;
}

// ---------- launch ----------
extern "C" void kernel_launch(void* const* d_in, const int* in_sizes, int n_in,
                              void* d_out, int out_size, void* d_ws, size_t ws_size,
                              hipStream_t stream) {
  const float* x     = (const float*)d_in[0];
  const float* rw    = (const float*)d_in[1];
  const float* sw1   = (const float*)d_in[2];
  const float* sw2   = (const float*)d_in[3];
  const float* sproj = (const float*)d_in[4];
  const float* ew1   = (const float*)d_in[5];
  const float* ew2   = (const float*)d_in[6];
  const float* eproj = (const float*)d_in[7];
  float* out   = (float*)d_out;
  float* probs = out + (size_t)NTOK * DIM;

  constexpr size_t SL = (size_t)HID * DIM;
  constexpr size_t off_xb   = 0;
  constexpr size_t off_w1t  = 6291456;
  constexpr size_t off_w2t  = off_w1t + 2 * 9 * SL;
  constexpr size_t off_pjt  = off_w2t + 2 * 9 * SL;
  constexpr size_t off_hid  = off_pjt + 2 * 9 * SL;              // 69,992,448
  constexpr size_t off_g2   = off_hid + (size_t)NSLOT * HID * 2; // 114,032,640
  constexpr size_t off_meta = off_g2 + (size_t)NSLOT * DIM * 4;  // 158,072,832

  char* ws = (char*)d_ws;
  u16*   xb   = (u16*)(ws + off_xb);
  u16*   w1t  = (u16*)(ws + off_w1t);
  u16*   w2t  = (u16*)(ws + off_w2t);
  u16*   pjt  = (u16*)(ws + off_pjt);
  u16*   hid  = (u16*)(ws + off_hid);
  float* g2   = (float*)(ws + off_g2);
  char*  meta = ws + off_meta;
  int*   topIdx  = (int*)meta;
  float* topW    = (float*)(meta + 32768);
  int*   listT   = (int*)(meta + 65536);
  float* listW   = (float*)(meta + 196608);
  int*   listP   = (int*)(meta + 327680);
  int*   cnt     = (int*)(meta + 458752);
  int*   tE1     = (int*)(meta + 459264);
  int*   tM1     = (int*)(meta + 459776);
  int*   tE2     = (int*)(meta + 460288);
  int*   tM2     = (int*)(meta + 460800);
  int*   slotTok = (int*)(meta + 461312);             // 57,344 B
  float* slotW   = (float*)(meta + 518656);           // 57,344 B
  int*   tokSlot = (int*)(meta + 576000);             // 32,768 B

  k_router<<<NTOK, 64, 0, stream>>>(x, rw, probs, topIdx, topW, xb);
  k_tr_all<<<dim3(HID / 64, DIM / 64, 27), dim3(64, 4), 0, stream>>>(
      ew1, sw1, ew2, sw2, eproj, sproj, w1t);

  k_build<<<NEXP, 256, 0, stream>>>(topIdx, topW, listT, listW, listP, cnt);
  k_tilemap<<<1, 256, 0, stream>>>(cnt, listT, listW, listP, tE1, tM1, tE2, tM2,
                                   slotTok, slotW, tokSlot);

  k_gemm1<<<MAXT1 * (HID / 128), 512, 0, stream>>>(xb, w1t, w2t, tE1, tM1,
                                                   slotTok, slotW, hid);
  k_gemm2<<<MAXT2 * (DIM / 128), 256, 0, stream>>>(hid, pjt, tE2, tM2, g2);
  k_combine<<<NTOK, 192, 0, stream>>>(g2, tokSlot, out);
}

// Round 9
// 198.311 us; speedup vs baseline: 1.5697x; 1.0857x over previous
//
#include <hip/hip_runtime.h>

typedef unsigned short u16;
typedef __bf16 bf16x8 __attribute__((ext_vector_type(8)));
typedef float f32x4 __attribute__((ext_vector_type(4)));

// ---------- helpers ----------
__device__ __forceinline__ u16 f2bf(float f) {
  union { float f; unsigned u; } v; v.f = f;
  return (u16)((v.u + 0x7fffu + ((v.u >> 16) & 1u)) >> 16);   // RNE
}

#define GLDS16(g, l)                                                          \
  __builtin_amdgcn_global_load_lds(                                           \
      (const __attribute__((address_space(1))) void*)(g),                     \
      (__attribute__((address_space(3))) void*)(l), 16, 0, 0)

#define SBAR()  __builtin_amdgcn_s_barrier()
#define SCHED() __builtin_amdgcn_sched_barrier(0)
#define VMCNT(n) asm volatile("s_waitcnt vmcnt(" #n ")" ::: "memory")

// ---------- sizes ----------
#define NTOK 4096     // B*T
#define DIM  768
#define HID  1536
#define NEXP 8
#define CAPR 10240    // routed slot capacity (8192 + per-expert pad to 256)
#define SHB  10240    // shared-expert slot base
#define NSLOT 14336   // CAPR + NTOK
#define MAXT1 56      // 256-row M-tiles: <=40 routed + 16 shared
#define MAXT2 112     // 128-row M-tiles (2 per 256-tile)

// ---------- fused transpose: 27 slices f32[R][C] -> bf16[C][R], 64x64 tiles ----------
__global__ __launch_bounds__(256) void k_tr_all(const float* __restrict__ ew1,
                                                const float* __restrict__ sw1,
                                                const float* __restrict__ ew2,
                                                const float* __restrict__ sw2,
                                                const float* __restrict__ eproj,
                                                const float* __restrict__ sproj,
                                                u16* __restrict__ dstBase) {
  __shared__ u16 tile[64][65];
  constexpr size_t SL = (size_t)HID * DIM;
  const int z = blockIdx.z;
  const float* src;
  int R, C, bxx = blockIdx.x, byy = blockIdx.y;
  if (z < 9)       { src = (z < 8) ? ew1 + (size_t)z * SL : sw1; R = DIM; C = HID; }
  else if (z < 18) { const int q = z - 9;  src = (q < 8) ? ew2 + (size_t)q * SL : sw2; R = DIM; C = HID; }
  else             { const int q = z - 18; src = (q < 8) ? eproj + (size_t)q * SL : sproj;
                     R = HID; C = DIM; const int t = bxx; bxx = byy; byy = t; }
  u16* dst = dstBase + (size_t)z * SL;
  const int c0 = bxx * 64, r0 = byy * 64;
  const int tx = threadIdx.x, ty = threadIdx.y;   // (64,4)
  #pragma unroll
  for (int i = 0; i < 16; i++)
    tile[ty + 4 * i][tx] = f2bf(src[(size_t)(r0 + ty + 4 * i) * C + c0 + tx]);
  __syncthreads();
  #pragma unroll
  for (int i = 0; i < 16; i++)
    dst[(size_t)(c0 + ty + 4 * i) * R + r0 + tx] = tile[tx][ty + 4 * i];
}

// ---------- router: 4 waves/block, one token per wave; probs + top-2 + x->bf16 ----------
__global__ __launch_bounds__(256) void k_router(const float* __restrict__ x,
                                                const float* __restrict__ rw,
                                                float* __restrict__ probs,
                                                int* __restrict__ topIdx,
                                                float* __restrict__ topW,
                                                u16* __restrict__ xb) {
  const int wv = threadIdx.x >> 6, lane = threadIdx.x & 63;
  const int t = blockIdx.x * 4 + wv;
  const float* xr = x + (size_t)t * DIM;
  u16* xbr = xb + (size_t)t * DIM;
  float acc[NEXP] = {0, 0, 0, 0, 0, 0, 0, 0};
  #pragma unroll
  for (int i = 0; i < DIM / 64; i++) {
    const int d = lane + 64 * i;
    const float xv = xr[d];
    xbr[d] = f2bf(xv);
    #pragma unroll
    for (int e = 0; e < NEXP; e++) acc[e] += xv * rw[e * DIM + d];
  }
  #pragma unroll
  for (int e = 0; e < NEXP; e++)
    #pragma unroll
    for (int s = 32; s > 0; s >>= 1) acc[e] += __shfl_xor(acc[e], s, 64);
  if (lane == 0) {
    float mx = acc[0];
    #pragma unroll
    for (int e = 1; e < NEXP; e++) mx = fmaxf(mx, acc[e]);
    float p[NEXP], sum = 0.f;
    #pragma unroll
    for (int e = 0; e < NEXP; e++) { p[e] = expf(acc[e] - mx); sum += p[e]; }
    const float inv = 1.f / sum;
    #pragma unroll
    for (int e = 0; e < NEXP; e++) p[e] *= inv;
    #pragma unroll
    for (int e = 0; e < NEXP; e++) probs[(size_t)t * NEXP + e] = p[e];
    int i1 = 0;
    #pragma unroll
    for (int e = 1; e < NEXP; e++) if (p[e] > p[i1]) i1 = e;
    int i2 = (i1 == 0) ? 1 : 0;
    #pragma unroll
    for (int e = 0; e < NEXP; e++) if (e != i1 && p[e] > p[i2]) i2 = e;
    const float s2 = 1.f / (p[i1] + p[i2]);
    topIdx[2 * t] = i1; topIdx[2 * t + 1] = i2;
    topW[2 * t] = p[i1] * s2; topW[2 * t + 1] = p[i2] * s2;
  }
}

// ---------- per-expert stable compaction (one block per expert) ----------
__global__ __launch_bounds__(256) void k_build(const int* __restrict__ topIdx,
                                               const float* __restrict__ topW,
                                               int* __restrict__ listT,
                                               float* __restrict__ listW,
                                               int* __restrict__ listP,
                                               int* __restrict__ cnt) {
  const int e = blockIdx.x;
  const int tid = threadIdx.x, w = tid >> 6, lane = tid & 63;
  __shared__ int wt[4];
  int base = 0;
  for (int c = 0; c < NTOK / 256; ++c) {
    const int t = c * 256 + tid;
    const int i0 = topIdx[2 * t], i1 = topIdx[2 * t + 1];
    const int pr = (i0 == e) ? 1 : ((i1 == e) ? 2 : 0);
    const unsigned long long m = __ballot(pr != 0);
    const int wl = __popcll(m & ((1ull << lane) - 1ull));
    if (lane == 0) wt[w] = __popcll(m);
    __syncthreads();
    int wbase = 0;
    #pragma unroll
    for (int j = 0; j < 4; j++) if (j < w) wbase += wt[j];
    if (pr) {
      const int pos = base + wbase + wl;
      listT[e * NTOK + pos] = t;
      listW[e * NTOK + pos] = (pr == 1) ? topW[2 * t] : topW[2 * t + 1];
      listP[e * NTOK + pos] = pr;
    }
    base += wt[0] + wt[1] + wt[2] + wt[3];
    __syncthreads();
  }
  if (tid == 0) cnt[e] = base;
}

// ---------- tile lists + offPad prefix (tiny, 1 block) ----------
__global__ __launch_bounds__(64) void k_maps(const int* __restrict__ cnt,
                                             int* __restrict__ tE1, int* __restrict__ tM1,
                                             int* __restrict__ tE2, int* __restrict__ tM2,
                                             int* __restrict__ offPad) {
  if (threadIdx.x == 0) {
    int tt = 0, acc = 0;
    for (int e = 0; e < NEXP; e++) {
      offPad[e] = acc;
      const int tiles = (cnt[e] + 255) >> 8;
      for (int i = 0; i < tiles; i++) { tE1[tt] = e; tM1[tt] = acc + i * 256; tt++; }
      acc += tiles * 256;
    }
    offPad[NEXP] = acc;
    for (int i = 0; i < NTOK / 256; i++) { tE1[tt] = NEXP; tM1[tt] = SHB + i * 256; tt++; }
    for (; tt < MAXT1; tt++) { tE1[tt] = -1; tM1[tt] = 0; }
    for (int j = 0; j < MAXT1; j++) {
      tE2[2 * j] = tE1[j];     tM2[2 * j] = tM1[j];
      tE2[2 * j + 1] = tE1[j]; tM2[2 * j + 1] = tM1[j] + 128;
    }
  }
}

// ---------- slot arrays (parallel across 56 blocks) ----------
__global__ __launch_bounds__(256) void k_slots(const int* __restrict__ offPad,
                                               const int* __restrict__ cnt,
                                               const int* __restrict__ listT,
                                               const float* __restrict__ listW,
                                               const int* __restrict__ listP,
                                               int* __restrict__ slotTok,
                                               float* __restrict__ slotW,
                                               int* __restrict__ tokSlot) {
  __shared__ int op[NEXP + 1];
  __shared__ int cs[NEXP];
  if (threadIdx.x < NEXP + 1) op[threadIdx.x] = offPad[threadIdx.x];
  if (threadIdx.x < NEXP) cs[threadIdx.x] = cnt[threadIdx.x];
  __syncthreads();
  const int s = blockIdx.x * 256 + threadIdx.x;
  if (s < CAPR) {
    int tok = 0; float wv = 0.f; int pp = 0;
    #pragma unroll
    for (int e = 0; e < NEXP; e++)
      if (s >= op[e] && s < op[e + 1]) {
        const int i = s - op[e];
        if (i < cs[e]) {
          tok = listT[e * NTOK + i];
          wv = listW[e * NTOK + i];
          pp = listP[e * NTOK + i];
        }
      }
    slotTok[s] = tok; slotW[s] = wv;
    if (pp) tokSlot[2 * tok + (pp - 1)] = s;    // deterministic: unique (tok,pp)
  } else {
    const int t = s - CAPR;
    slotTok[SHB + t] = t; slotW[SHB + t] = 1.f;
  }
}

// ---------- gemm1: 8-phase 256x128xBK64, 8 waves (4Mx2N), dual-B (FROZEN from r8) ----
__global__ __launch_bounds__(512, 2) void k_gemm1(const u16* __restrict__ xb,
                                                  const u16* __restrict__ w1t,
                                                  const u16* __restrict__ w2t,
                                                  const int* __restrict__ tE1,
                                                  const int* __restrict__ tM1,
                                                  const int* __restrict__ slotTok,
                                                  const float* __restrict__ slotW,
                                                  u16* __restrict__ hidden) {
  __shared__ alignas(16) u16 L[2][32768];
  const int bid = blockIdx.x;                       // 672 = 8*84
  const int wgid = (bid & 7) * 84 + (bid >> 3);
  const int bx = wgid % MAXT1, by = wgid / MAXT1;
  const int e = tE1[bx];
  if (e < 0) return;
  const int m0 = tM1[bx];
  const int nBase = by * 128;
  constexpr size_t SL = (size_t)HID * DIM;
  const u16* w1 = w1t + (size_t)e * SL;
  const u16* w2 = w2t + (size_t)e * SL;
  const int tid = threadIdx.x, w = tid >> 6, lane = tid & 63;
  const int wr = w >> 1, wc = w & 1;

  const int srow = tid >> 2;
  const int kcol = ((tid & 3) ^ ((tid >> 3) & 3)) * 8;
  const int tokA0 = slotTok[m0 + srow];
  const int tokA1 = slotTok[m0 + 128 + srow];
  const u16* gA0 = xb + (size_t)tokA0 * DIM + kcol;
  const u16* gA1 = xb + (size_t)tokA1 * DIM + kcol;
  const u16* gB1 = w1 + (size_t)(nBase + srow) * DIM + kcol;
  const u16* gB2 = w2 + (size_t)(nBase + srow) * DIM + kcol;
  const int dA0 = tid * 8, dA1 = 4096 + tid * 8, dB = tid * 8;

  const int rl = lane & 15;
  const int kq = lane >> 4;
  const int aBase = (wr * 64 + rl) * 32 + (kq ^ ((rl >> 1) & 3)) * 8;
  const int bBase = (wc * 64 + rl) * 32 + (kq ^ ((rl >> 1) & 3)) * 8;

  f32x4 acc1[4][4], acc2[4][4];
  const f32x4 vz = {0.f, 0.f, 0.f, 0.f};
  #pragma unroll
  for (int m = 0; m < 4; m++)
    #pragma unroll
    for (int n = 0; n < 4; n++) { acc1[m][n] = vz; acc2[m][n] = vz; }

#define G1_STA(d, koff, kh) do {                                              \
    GLDS16(gA0 + (koff), &L[d][(kh) * 8192 + dA0]);                           \
    GLDS16(gA1 + (koff), &L[d][(kh) * 8192 + dA1]); } while (0)
#define G1_STB(d, koff, kh) do {                                              \
    GLDS16(gB1 + (koff), &L[d][16384 + (kh) * 4096 + dB]);                    \
    GLDS16(gB2 + (koff), &L[d][24576 + (kh) * 4096 + dB]); } while (0)
#define G1_RDB(d, kh) do { _Pragma("unroll")                                  \
    for (int n = 0; n < 4; n++) {                                             \
      b1v[n] = *(const bf16x8*)&L[d][16384 + (kh) * 4096 + bBase + n * 512];  \
      b2v[n] = *(const bf16x8*)&L[d][24576 + (kh) * 4096 + bBase + n * 512]; } } while (0)
#define G1_RDA(d, kh, mp) do { _Pragma("unroll")                              \
    for (int j = 0; j < 2; j++)                                               \
      av[j] = *(const bf16x8*)&L[d][(kh) * 8192 + aBase + ((mp) * 2 + j) * 512]; } while (0)
#define G1_MM(mp) do { __builtin_amdgcn_s_setprio(1);                         \
    _Pragma("unroll") for (int j = 0; j < 2; j++)                             \
      _Pragma("unroll") for (int n = 0; n < 4; n++) {                         \
        acc1[(mp) * 2 + j][n] = __builtin_amdgcn_mfma_f32_16x16x32_bf16(av[j], b1v[n], acc1[(mp) * 2 + j][n], 0, 0, 0); \
        acc2[(mp) * 2 + j][n] = __builtin_amdgcn_mfma_f32_16x16x32_bf16(av[j], b2v[n], acc2[(mp) * 2 + j][n], 0, 0, 0); } \
    __builtin_amdgcn_s_setprio(0); } while (0)

  G1_STA(0, 0, 0);  G1_STB(0, 0, 0);
  G1_STA(0, 32, 1); G1_STB(0, 32, 1);
  G1_STA(1, 64, 0); G1_STB(1, 64, 0);
  SCHED(); VMCNT(8); SBAR(); SCHED();

  bf16x8 av[2], b1v[4], b2v[4];
  for (int i = 0; i < 5; i++) {
    const int kOff = i * 128;
    G1_RDB(0, 0); G1_RDA(0, 0, 0); SCHED(); G1_STA(1, kOff + 96, 1); SCHED();
    G1_MM(0); SCHED(); SBAR(); SCHED();
    G1_RDA(0, 0, 1); SCHED(); G1_STB(1, kOff + 96, 1); SCHED();
    G1_MM(1); SCHED(); VMCNT(8); SBAR(); SCHED();
    G1_RDB(0, 1); G1_RDA(0, 1, 0); SCHED(); G1_STA(0, kOff + 128, 0); SCHED();
    G1_MM(0); SCHED(); SBAR(); SCHED();
    G1_RDA(0, 1, 1); SCHED(); G1_STB(0, kOff + 128, 0); SCHED();
    G1_MM(1); SCHED(); VMCNT(8); SBAR(); SCHED();
    G1_RDB(1, 0); G1_RDA(1, 0, 0); SCHED(); G1_STA(0, kOff + 160, 1); SCHED();
    G1_MM(0); SCHED(); SBAR(); SCHED();
    G1_RDA(1, 0, 1); SCHED(); G1_STB(0, kOff + 160, 1); SCHED();
    G1_MM(1); SCHED(); VMCNT(8); SBAR(); SCHED();
    G1_RDB(1, 1); G1_RDA(1, 1, 0); SCHED(); G1_STA(1, kOff + 192, 0); SCHED();
    G1_MM(0); SCHED(); SBAR(); SCHED();
    G1_RDA(1, 1, 1); SCHED(); G1_STB(1, kOff + 192, 0); SCHED();
    G1_MM(1); SCHED(); VMCNT(8); SBAR(); SCHED();
  }
  G1_RDB(0, 0); G1_RDA(0, 0, 0); SCHED(); G1_STA(1, 736, 1); SCHED();
  G1_MM(0); SCHED(); SBAR(); SCHED();
  G1_RDA(0, 0, 1); SCHED(); G1_STB(1, 736, 1); SCHED();
  G1_MM(1); SCHED(); VMCNT(8); SBAR(); SCHED();
  G1_RDB(0, 1); G1_RDA(0, 1, 0); SCHED(); G1_MM(0); SCHED(); SBAR(); SCHED();
  G1_RDA(0, 1, 1); SCHED(); G1_MM(1); SCHED(); VMCNT(4); SBAR(); SCHED();
  G1_RDB(1, 0); G1_RDA(1, 0, 0); SCHED(); G1_MM(0); SCHED(); SBAR(); SCHED();
  G1_RDA(1, 0, 1); SCHED(); G1_MM(1); SCHED(); VMCNT(0); SBAR(); SCHED();
  G1_RDB(1, 1); G1_RDA(1, 1, 0); SCHED(); G1_MM(0); SCHED(); SBAR(); SCHED();
  G1_RDA(1, 1, 1); SCHED(); G1_MM(1);
#undef G1_STA
#undef G1_STB
#undef G1_RDB
#undef G1_RDA
#undef G1_MM

  #pragma unroll
  for (int m = 0; m < 4; m++)
    #pragma unroll
    for (int r = 0; r < 4; r++) {
      const int slot = m0 + wr * 64 + m * 16 + (lane >> 4) * 4 + r;
      const float cwv = slotW[slot];
      #pragma unroll
      for (int n = 0; n < 4; n++) {
        const int hcol = nBase + wc * 64 + n * 16 + (lane & 15);
        const float v1 = acc1[m][n][r], v2 = acc2[m][n][r];
        hidden[(size_t)slot * HID + hcol] = f2bf((v1 / (1.f + __expf(-v1))) * v2 * cwv);
      }
    }
}

// ---------- gemm2: 8-phase 128x128xBK64, 4 waves (2Mx2N), single-B, 64KB LDS (2/CU) ----
// Same proven calendar as gemm1: units {A-kh(2 glds), B-kh(2)}, VMCNT(8) odd phases,
// tail 8/4/0. K=1536 -> 24 tiles, 11 loop iters + 2-tile tail.
__global__ __launch_bounds__(256, 2) void k_gemm2(const u16* __restrict__ hid,
                                                  const u16* __restrict__ pjt,
                                                  const int* __restrict__ tE2,
                                                  const int* __restrict__ tM2,
                                                  float* __restrict__ g2) {
  __shared__ alignas(16) u16 L[2][16384];
  const int bid = blockIdx.x;                      // 672 = 8*84
  const int wgid = (bid & 7) * 84 + (bid >> 3);
  const int bx = wgid % MAXT2, by = wgid / MAXT2;
  const int e = tE2[bx];
  if (e < 0) return;
  const int m0 = tM2[bx];
  const int nBase = by * 128;
  constexpr size_t SL = (size_t)HID * DIM;
  const u16* pj = pjt + (size_t)e * SL;
  const int tid = threadIdx.x, w = tid >> 6, lane = tid & 63;
  const int wr = w >> 1, wc = w & 1;

  // staging: chunk c in {tid, tid+256}; row = c>>2 (0..127), swizzled 16B col
  const int r0 = tid >> 2;
  const int kcol = ((tid & 3) ^ ((tid >> 3) & 3)) * 8;
  const u16* gA0 = hid + (size_t)(m0 + r0) * HID + kcol;
  const u16* gA1 = hid + (size_t)(m0 + 64 + r0) * HID + kcol;
  const u16* gB0 = pj + (size_t)(nBase + r0) * HID + kcol;
  const u16* gB1p = pj + (size_t)(nBase + 64 + r0) * HID + kcol;
  const int d0 = tid * 8, d1 = 2048 + tid * 8;

  const int rl = lane & 15;
  const int kq = lane >> 4;
  const int aBase = (wr * 64 + rl) * 32 + (kq ^ ((rl >> 1) & 3)) * 8;
  const int bBase = (wc * 64 + rl) * 32 + (kq ^ ((rl >> 1) & 3)) * 8;

  f32x4 acc[4][4];
  const f32x4 vz = {0.f, 0.f, 0.f, 0.f};
  #pragma unroll
  for (int m = 0; m < 4; m++)
    #pragma unroll
    for (int n = 0; n < 4; n++) acc[m][n] = vz;

#define G2_STA(d, koff, kh) do {                                              \
    GLDS16(gA0 + (koff), &L[d][(kh) * 4096 + d0]);                            \
    GLDS16(gA1 + (koff), &L[d][(kh) * 4096 + d1]); } while (0)
#define G2_STB(d, koff, kh) do {                                              \
    GLDS16(gB0 + (koff), &L[d][8192 + (kh) * 4096 + d0]);                     \
    GLDS16(gB1p + (koff), &L[d][8192 + (kh) * 4096 + d1]); } while (0)
#define G2_RDB(d, kh) do { _Pragma("unroll")                                  \
    for (int n = 0; n < 4; n++)                                               \
      bv[n] = *(const bf16x8*)&L[d][8192 + (kh) * 4096 + bBase + n * 512]; } while (0)
#define G2_RDA(d, kh, mp) do { _Pragma("unroll")                              \
    for (int j = 0; j < 2; j++)                                               \
      av[j] = *(const bf16x8*)&L[d][(kh) * 4096 + aBase + ((mp) * 2 + j) * 512]; } while (0)
#define G2_MM(mp) do { __builtin_amdgcn_s_setprio(1);                         \
    _Pragma("unroll") for (int j = 0; j < 2; j++)                             \
      _Pragma("unroll") for (int n = 0; n < 4; n++)                           \
        acc[(mp) * 2 + j][n] = __builtin_amdgcn_mfma_f32_16x16x32_bf16(av[j], bv[n], acc[(mp) * 2 + j][n], 0, 0, 0); \
    __builtin_amdgcn_s_setprio(0); } while (0)

  G2_STA(0, 0, 0);  G2_STB(0, 0, 0);
  G2_STA(0, 32, 1); G2_STB(0, 32, 1);
  G2_STA(1, 64, 0); G2_STB(1, 64, 0);
  SCHED(); VMCNT(8); SBAR(); SCHED();

  bf16x8 av[2], bv[4];
  for (int i = 0; i < 11; i++) {
    const int kOff = i * 128;
    G2_RDB(0, 0); G2_RDA(0, 0, 0); SCHED(); G2_STA(1, kOff + 96, 1); SCHED();
    G2_MM(0); SCHED(); SBAR(); SCHED();
    G2_RDA(0, 0, 1); SCHED(); G2_STB(1, kOff + 96, 1); SCHED();
    G2_MM(1); SCHED(); VMCNT(8); SBAR(); SCHED();
    G2_RDB(0, 1); G2_RDA(0, 1, 0); SCHED(); G2_STA(0, kOff + 128, 0); SCHED();
    G2_MM(0); SCHED(); SBAR(); SCHED();
    G2_RDA(0, 1, 1); SCHED(); G2_STB(0, kOff + 128, 0); SCHED();
    G2_MM(1); SCHED(); VMCNT(8); SBAR(); SCHED();
    G2_RDB(1, 0); G2_RDA(1, 0, 0); SCHED(); G2_STA(0, kOff + 160, 1); SCHED();
    G2_MM(0); SCHED(); SBAR(); SCHED();
    G2_RDA(1, 0, 1); SCHED(); G2_STB(0, kOff + 160, 1); SCHED();
    G2_MM(1); SCHED(); VMCNT(8); SBAR(); SCHED();
    G2_RDB(1, 1); G2_RDA(1, 1, 0); SCHED(); G2_STA(1, kOff + 192, 0); SCHED();
    G2_MM(0); SCHED(); SBAR(); SCHED();
    G2_RDA(1, 1, 1); SCHED(); G2_STB(1, kOff + 192, 0); SCHED();
    G2_MM(1); SCHED(); VMCNT(8); SBAR(); SCHED();
  }
  // tail: tiles 22 (buf0), 23 (buf1); last stage = t23 kh1 @ k=1504
  G2_RDB(0, 0); G2_RDA(0, 0, 0); SCHED(); G2_STA(1, 1504, 1); SCHED();
  G2_MM(0); SCHED(); SBAR(); SCHED();
  G2_RDA(0, 0, 1); SCHED(); G2_STB(1, 1504, 1); SCHED();
  G2_MM(1); SCHED(); VMCNT(8); SBAR(); SCHED();
  G2_RDB(0, 1); G2_RDA(0, 1, 0); SCHED(); G2_MM(0); SCHED(); SBAR(); SCHED();
  G2_RDA(0, 1, 1); SCHED(); G2_MM(1); SCHED(); VMCNT(4); SBAR(); SCHED();
  G2_RDB(1, 0); G2_RDA(1, 0, 0); SCHED(); G2_MM(0); SCHED(); SBAR(); SCHED();
  G2_RDA(1, 0, 1); SCHED(); G2_MM(1); SCHED(); VMCNT(0); SBAR(); SCHED();
  G2_RDB(1, 1); G2_RDA(1, 1, 0); SCHED(); G2_MM(0); SCHED(); SBAR(); SCHED();
  G2_RDA(1, 1, 1); SCHED(); G2_MM(1);
#undef G2_STA
#undef G2_STB
#undef G2_RDB
#undef G2_RDA
#undef G2_MM

  #pragma unroll
  for (int m = 0; m < 4; m++)
    #pragma unroll
    for (int r = 0; r < 4; r++) {
      const int slot = m0 + wr * 64 + m * 16 + (lane >> 4) * 4 + r;
      #pragma unroll
      for (int n = 0; n < 4; n++) {
        const int dcol = nBase + wc * 64 + n * 16 + (lane & 15);
        g2[(size_t)slot * DIM + dcol] = acc[m][n][r];
      }
    }
}

// ---------- combine ----------
__global__ __launch_bounds__(192) void k_combine(const float* __restrict__ g2,
                                                 const int* __restrict__ tokSlot,
                                                 float* __restrict__ out) {
  const int t = blockIdx.x, d4 = threadIdx.x;
  const int sA = tokSlot[2 * t], sB = tokSlot[2 * t + 1];
  const int lo = sA < sB ? sA : sB;
  const int hi = sA < sB ? sB : sA;
  const float4 a = ((const float4*)(g2 + (size_t)lo * DIM))[d4];
  const float4 b = ((const float4*)(g2 + (size_t)hi * DIM))[d4];
  const float4 c = ((const float4*)(g2 + (size_t)(SHB + t) * DIM))[d4];
  float4 o;
  o.x = a.x + b.x + c.x; o.y = a.y + b.y + c.y;
  o.z = a.z + b.z + c.z; o.w = a.w + b.w + c.w;
  ((float4*)(out + (size_t)t * DIM))[d4] = o;
}

// ---------- launch ----------
extern "C" void kernel_launch(void* const* d_in, const int* in_sizes, int n_in,
                              void* d_out, int out_size, void* d_ws, size_t ws_size,
                              hipStream_t stream) {
  const float* x     = (const float*)d_in[0];
  const float* rw    = (const float*)d_in[1];
  const float* sw1   = (const float*)d_in[2];
  const float* sw2   = (const float*)d_in[3];
  const float* sproj = (const float*)d_in[4];
  const float* ew1   = (const float*)d_in[5];
  const float* ew2   = (const float*)d_in[6];
  const float* eproj = (const float*)d_in[7];
  float* out   = (float*)d_out;
  float* probs = out + (size_t)NTOK * DIM;

  constexpr size_t SL = (size_t)HID * DIM;
  constexpr size_t off_xb   = 0;
  constexpr size_t off_w1t  = 6291456;
  constexpr size_t off_w2t  = off_w1t + 2 * 9 * SL;
  constexpr size_t off_pjt  = off_w2t + 2 * 9 * SL;
  constexpr size_t off_hid  = off_pjt + 2 * 9 * SL;              // 69,992,448
  constexpr size_t off_g2   = off_hid + (size_t)NSLOT * HID * 2; // 114,032,640
  constexpr size_t off_meta = off_g2 + (size_t)NSLOT * DIM * 4;  // 158,072,832

  char* ws = (char*)d_ws;
  u16*   xb   = (u16*)(ws + off_xb);
  u16*   w1t  = (u16*)(ws + off_w1t);
  u16*   w2t  = (u16*)(ws + off_w2t);
  u16*   pjt  = (u16*)(ws + off_pjt);
  u16*   hid  = (u16*)(ws + off_hid);
  float* g2   = (float*)(ws + off_g2);
  char*  meta = ws + off_meta;
  int*   topIdx  = (int*)meta;
  float* topW    = (float*)(meta + 32768);
  int*   listT   = (int*)(meta + 65536);
  float* listW   = (float*)(meta + 196608);
  int*   listP   = (int*)(meta + 327680);
  int*   cnt     = (int*)(meta + 458752);
  int*   tE1     = (int*)(meta + 459264);
  int*   tM1     = (int*)(meta + 459776);
  int*   tE2     = (int*)(meta + 460288);
  int*   tM2     = (int*)(meta + 460800);
  int*   slotTok = (int*)(meta + 461312);             // 57,344 B
  float* slotW   = (float*)(meta + 518656);           // 57,344 B
  int*   tokSlot = (int*)(meta + 576000);             // 32,768 B
  int*   offPad  = (int*)(meta + 608768);             // 64 B

  k_router<<<NTOK / 4, 256, 0, stream>>>(x, rw, probs, topIdx, topW, xb);
  k_tr_all<<<dim3(HID / 64, DIM / 64, 27), dim3(64, 4), 0, stream>>>(
      ew1, sw1, ew2, sw2, eproj, sproj, w1t);

  k_build<<<NEXP, 256, 0, stream>>>(topIdx, topW, listT, listW, listP, cnt);
  k_maps<<<1, 64, 0, stream>>>(cnt, tE1, tM1, tE2, tM2, offPad);
  k_slots<<<NSLOT / 256, 256, 0, stream>>>(offPad, cnt, listT, listW, listP,
                                           slotTok, slotW, tokSlot);

  k_gemm1<<<MAXT1 * (HID / 128), 512, 0, stream>>>(xb, w1t, w2t, tE1, tM1,
                                                   slotTok, slotW, hid);
  k_gemm2<<<MAXT2 * (DIM / 128), 256, 0, stream>>>(hid, pjt, tE2, tM2, g2);
  k_combine<<<NTOK, 192, 0, stream>>>(g2, tokSlot, out);
}